// Round 1
// baseline (2637.566 us; speedup 1.0000x reference)
//
#include <hip/hip_runtime.h>
#include <cstddef>

#define L_SEQ 784
#define DIM 384
#define B_SZ 16
#define NH 8
#define QKD 32
#define VD 128
#define EDIM 1536   // NH*(2*QKD+VD)
#define RESN 25
#define NPTS 625    // RESN*RESN
#define ODIM 1024   // NH*VD
#define QTILES 49   // L_SEQ / 16

// ---------------------------------------------------------------------------
// cubic interpolation weight (a = -0.75), matches reference _cubic_weight
// ---------------------------------------------------------------------------
__device__ __forceinline__ float cubic_w(float x) {
    float ax = fabsf(x);
    const float a = -0.75f;
    float w1 = ((a + 2.0f) * ax - (a + 3.0f)) * ax * ax + 1.0f;
    float w2 = a * (((ax - 5.0f) * ax + 8.0f) * ax - 4.0f);
    return ax <= 1.0f ? w1 : (ax < 2.0f ? w2 : 0.0f);
}

// ---------------------------------------------------------------------------
// Build interp tables: for each output position o in [0,784):
//   4 weights + 4 clipped source indices (decomposed into y,x on the 25x25 grid)
// ---------------------------------------------------------------------------
__global__ void interp_tab_kernel(float* __restrict__ wtab,
                                  int* __restrict__ iyb,
                                  int* __restrict__ ixb) {
    int o = blockIdx.x * blockDim.x + threadIdx.x;
    if (o >= L_SEQ) return;
    const float scale = 625.0f / 784.0f;
    float src = ((float)o + 0.5f) * scale - 0.5f;
    float f = floorf(src);
    float t = src - f;
    int fi = (int)f;
    float w[4];
    w[0] = cubic_w(t + 1.0f);
    w[1] = cubic_w(t);
    w[2] = cubic_w(1.0f - t);
    w[3] = cubic_w(2.0f - t);
#pragma unroll
    for (int j = 0; j < 4; ++j) {
        int idx = fi - 1 + j;
        idx = idx < 0 ? 0 : (idx > NPTS - 1 ? NPTS - 1 : idx);
        wtab[o * 4 + j] = w[j];
        iyb[o * 4 + j] = idx / RESN;
        ixb[o * 4 + j] = idx % RESN;
    }
}

// ---------------------------------------------------------------------------
// bias[h][o][p] = sum_{a,b} w_o[a] w_p[b] table[h][ |dy|*25 + |dx| ]
// (exploits 4-nonzeros-per-row sparsity of the interp matrix M)
// ---------------------------------------------------------------------------
__global__ __launch_bounds__(256) void bias_kernel(const float* __restrict__ table,
                                                   const float* __restrict__ wtab,
                                                   const int* __restrict__ iyb,
                                                   const int* __restrict__ ixb,
                                                   float* __restrict__ bias) {
    int idx = blockIdx.x * 256 + threadIdx.x;
    const int total = NH * L_SEQ * L_SEQ;
    if (idx >= total) return;
    int h = idx / (L_SEQ * L_SEQ);
    int rem = idx - h * (L_SEQ * L_SEQ);
    int o = rem / L_SEQ;
    int p = rem - o * L_SEQ;
    const float* th = table + h * NPTS;
    float wo[4], wp[4];
    int oy[4], ox[4], py[4], px[4];
#pragma unroll
    for (int a = 0; a < 4; ++a) {
        wo[a] = wtab[o * 4 + a]; oy[a] = iyb[o * 4 + a]; ox[a] = ixb[o * 4 + a];
        wp[a] = wtab[p * 4 + a]; py[a] = iyb[p * 4 + a]; px[a] = ixb[p * 4 + a];
    }
    float s = 0.0f;
#pragma unroll
    for (int a = 0; a < 4; ++a) {
#pragma unroll
        for (int b = 0; b < 4; ++b) {
            int dy = abs(oy[a] - py[b]);
            int dx = abs(ox[a] - px[b]);
            s += wo[a] * wp[b] * th[dy * RESN + dx];
        }
    }
    bias[idx] = s;
}

// ---------------------------------------------------------------------------
// qkv GEMM: C[m,n] = sum_k X[m,k] * Wqkv[n,k];  M=12544, N=1536, K=384
// scatters into q[bh][l][32], k[bh][l][32], v[bh][l][128] with bh = b*8+h
// ---------------------------------------------------------------------------
__global__ __launch_bounds__(256) void qkv_gemm_kernel(const float* __restrict__ X,
                                                       const float* __restrict__ W,
                                                       float* __restrict__ qb,
                                                       float* __restrict__ kb,
                                                       float* __restrict__ vb) {
    __shared__ float As[16][68];
    __shared__ float Bs[16][68];
    int tid = threadIdx.x;
    int m0 = blockIdx.x * 64;
    int n0 = blockIdx.y * 64;
    int tx = tid & 15, ty = tid >> 4;
    int lr = tid >> 2;          // 0..63 (row within tile for the staging load)
    int lk = (tid & 3) * 4;     // 0,4,8,12 (k offset)
    float acc[4][4] = {};
    for (int k0 = 0; k0 < DIM; k0 += 16) {
        float4 av = *(const float4*)(X + (size_t)(m0 + lr) * DIM + k0 + lk);
        float4 bv = *(const float4*)(W + (size_t)(n0 + lr) * DIM + k0 + lk);
        __syncthreads();
        As[lk + 0][lr] = av.x; As[lk + 1][lr] = av.y; As[lk + 2][lr] = av.z; As[lk + 3][lr] = av.w;
        Bs[lk + 0][lr] = bv.x; Bs[lk + 1][lr] = bv.y; Bs[lk + 2][lr] = bv.z; Bs[lk + 3][lr] = bv.w;
        __syncthreads();
#pragma unroll
        for (int kk = 0; kk < 16; ++kk) {
            float4 a = *(const float4*)&As[kk][ty * 4];
            float4 b = *(const float4*)&Bs[kk][tx * 4];
            acc[0][0] += a.x * b.x; acc[0][1] += a.x * b.y; acc[0][2] += a.x * b.z; acc[0][3] += a.x * b.w;
            acc[1][0] += a.y * b.x; acc[1][1] += a.y * b.y; acc[1][2] += a.y * b.z; acc[1][3] += a.y * b.w;
            acc[2][0] += a.z * b.x; acc[2][1] += a.z * b.y; acc[2][2] += a.z * b.z; acc[2][3] += a.z * b.w;
            acc[3][0] += a.w * b.x; acc[3][1] += a.w * b.y; acc[3][2] += a.w * b.z; acc[3][3] += a.w * b.w;
        }
    }
#pragma unroll
    for (int i = 0; i < 4; ++i) {
        int m = m0 + ty * 4 + i;
        int bidx = m / L_SEQ;
        int l = m - bidx * L_SEQ;
#pragma unroll
        for (int j = 0; j < 4; ++j) {
            int n = n0 + tx * 4 + j;
            int head = n / 192;
            int rr = n - head * 192;
            size_t bh = (size_t)bidx * NH + head;
            float val = acc[i][j];
            if (rr < QKD) {
                qb[(bh * L_SEQ + l) * QKD + rr] = val;
            } else if (rr < 2 * QKD) {
                kb[(bh * L_SEQ + l) * QKD + (rr - QKD)] = val;
            } else {
                vb[(bh * L_SEQ + l) * VD + (rr - 2 * QKD)] = val;
            }
        }
    }
}

// ---------------------------------------------------------------------------
// attention: one block per (b,h,q-tile of 16 rows)
// scores tile kept entirely in LDS (16 x 784 fp32 = 49KB); softmax via
// 16-lane shuffle groups; PV with v from L1/L2-cached global.
// writes o2[b][l][h*128 + d]
// ---------------------------------------------------------------------------
__global__ __launch_bounds__(256) void attn_kernel(const float* __restrict__ qg,
                                                   const float* __restrict__ kg,
                                                   const float* __restrict__ vg,
                                                   const float* __restrict__ bias,
                                                   float* __restrict__ o2) {
    __shared__ float sc[16 * L_SEQ];
    __shared__ float qs[16 * QKD];
    int tid = threadIdx.x;
    int bh = blockIdx.x / QTILES;
    int qt = blockIdx.x - bh * QTILES;
    int b = bh / NH;
    int h = bh - b * NH;
    int q0 = qt * 16;
    const float* qp = qg + ((size_t)bh * L_SEQ + q0) * QKD;
    const float* kp = kg + (size_t)bh * L_SEQ * QKD;
    const float* vp = vg + (size_t)bh * L_SEQ * VD;
    const float* bp = bias + ((size_t)h * L_SEQ + q0) * L_SEQ;

    for (int i = tid; i < 16 * QKD; i += 256) qs[i] = qp[i];
    __syncthreads();

    const float scale = 0.17677669529663687f;  // 32^-0.5
    // ---- scores: 16*784 elements, 49 per thread ----
    {
        int r = 0, c = tid;  // tid < 784 so r starts at 0
        for (int it = 0; it < QTILES; ++it) {
            int lin = it * 256 + tid;
            const float4* kr = (const float4*)(kp + (size_t)c * QKD);
            const float4* qr = (const float4*)(qs + r * QKD);
            float acc = 0.0f;
#pragma unroll
            for (int j = 0; j < 8; ++j) {
                float4 kv = kr[j], qv = qr[j];
                acc += kv.x * qv.x + kv.y * qv.y + kv.z * qv.z + kv.w * qv.w;
            }
            sc[lin] = acc * scale + bp[lin];
            c += 256;
            if (c >= L_SEQ) { c -= L_SEQ; ++r; }
        }
    }
    __syncthreads();

    // ---- softmax: row = tid/16, 16 lanes per row ----
    {
        int r = tid >> 4;
        int g = tid & 15;
        float mx = -1e30f;
        for (int c = g; c < L_SEQ; c += 16) mx = fmaxf(mx, sc[r * L_SEQ + c]);
#pragma unroll
        for (int m = 1; m < 16; m <<= 1) mx = fmaxf(mx, __shfl_xor(mx, m, 64));
        float sum = 0.0f;
        for (int c = g; c < L_SEQ; c += 16) {
            float e = __expf(sc[r * L_SEQ + c] - mx);
            sc[r * L_SEQ + c] = e;
            sum += e;
        }
#pragma unroll
        for (int m = 1; m < 16; m <<= 1) sum += __shfl_xor(sum, m, 64);
        float inv = 1.0f / sum;
        for (int c = g; c < L_SEQ; c += 16) sc[r * L_SEQ + c] *= inv;
    }
    __syncthreads();

    // ---- PV: row = tid/16, cols (tid&15)*8 .. +7 ----
    {
        int r = tid >> 4;
        int g = tid & 15;
        float acc[8] = {};
        const float* scr = sc + r * L_SEQ;
        for (int kk = 0; kk < L_SEQ; ++kk) {
            float p = scr[kk];
            const float4* vv = (const float4*)(vp + (size_t)kk * VD + g * 8);
            float4 v0 = vv[0], v1 = vv[1];
            acc[0] += p * v0.x; acc[1] += p * v0.y; acc[2] += p * v0.z; acc[3] += p * v0.w;
            acc[4] += p * v1.x; acc[5] += p * v1.y; acc[6] += p * v1.z; acc[7] += p * v1.w;
        }
        float* op = o2 + ((size_t)b * L_SEQ + q0 + r) * ODIM + h * VD + g * 8;
#pragma unroll
        for (int j = 0; j < 8; ++j) op[j] = acc[j];
    }
}

// ---------------------------------------------------------------------------
// output projection: out[m,n] = sum_e o2[m,e]*Wproj[n,e] + bproj[n]
// M=12544, N=384, K=1024
// ---------------------------------------------------------------------------
__global__ __launch_bounds__(256) void proj_gemm_kernel(const float* __restrict__ X,
                                                        const float* __restrict__ W,
                                                        const float* __restrict__ bproj,
                                                        float* __restrict__ out) {
    __shared__ float As[16][68];
    __shared__ float Bs[16][68];
    int tid = threadIdx.x;
    int m0 = blockIdx.x * 64;
    int n0 = blockIdx.y * 64;
    int tx = tid & 15, ty = tid >> 4;
    int lr = tid >> 2;
    int lk = (tid & 3) * 4;
    float acc[4][4] = {};
    for (int k0 = 0; k0 < ODIM; k0 += 16) {
        float4 av = *(const float4*)(X + (size_t)(m0 + lr) * ODIM + k0 + lk);
        float4 bv = *(const float4*)(W + (size_t)(n0 + lr) * ODIM + k0 + lk);
        __syncthreads();
        As[lk + 0][lr] = av.x; As[lk + 1][lr] = av.y; As[lk + 2][lr] = av.z; As[lk + 3][lr] = av.w;
        Bs[lk + 0][lr] = bv.x; Bs[lk + 1][lr] = bv.y; Bs[lk + 2][lr] = bv.z; Bs[lk + 3][lr] = bv.w;
        __syncthreads();
#pragma unroll
        for (int kk = 0; kk < 16; ++kk) {
            float4 a = *(const float4*)&As[kk][ty * 4];
            float4 b = *(const float4*)&Bs[kk][tx * 4];
            acc[0][0] += a.x * b.x; acc[0][1] += a.x * b.y; acc[0][2] += a.x * b.z; acc[0][3] += a.x * b.w;
            acc[1][0] += a.y * b.x; acc[1][1] += a.y * b.y; acc[1][2] += a.y * b.z; acc[1][3] += a.y * b.w;
            acc[2][0] += a.z * b.x; acc[2][1] += a.z * b.y; acc[2][2] += a.z * b.z; acc[2][3] += a.z * b.w;
            acc[3][0] += a.w * b.x; acc[3][1] += a.w * b.y; acc[3][2] += a.w * b.z; acc[3][3] += a.w * b.w;
        }
    }
#pragma unroll
    for (int i = 0; i < 4; ++i) {
        int m = m0 + ty * 4 + i;
#pragma unroll
        for (int j = 0; j < 4; ++j) {
            int n = n0 + tx * 4 + j;
            out[(size_t)m * DIM + n] = acc[i][j] + bproj[n];
        }
    }
}

// ---------------------------------------------------------------------------
// launch
// ---------------------------------------------------------------------------
extern "C" void kernel_launch(void* const* d_in, const int* in_sizes, int n_in,
                              void* d_out, int out_size, void* d_ws, size_t ws_size,
                              hipStream_t stream) {
    const float* x      = (const float*)d_in[0];  // (16,784,384)
    const float* Wqkv   = (const float*)d_in[1];  // (1536,384)
    const float* Wproj  = (const float*)d_in[2];  // (384,1024)
    const float* bproj  = (const float*)d_in[3];  // (384,)
    const float* table  = (const float*)d_in[4];  // (8,625)
    // d_in[5] = bias_idxs (unused: reconstructed analytically)
    float* out = (float*)d_out;

    // workspace layout (floats)
    const size_t QK_SZ = (size_t)B_SZ * NH * L_SEQ * QKD;   // 3,211,264
    const size_t V_SZ  = (size_t)B_SZ * NH * L_SEQ * VD;    // 12,845,056
    const size_t BI_SZ = (size_t)NH * L_SEQ * L_SEQ;        // 4,917,248
    const size_t O2_SZ = (size_t)B_SZ * L_SEQ * ODIM;       // 12,845,056

    float* ws   = (float*)d_ws;
    float* qb   = ws;
    float* kb   = qb + QK_SZ;
    float* vb   = kb + QK_SZ;
    float* bias = vb + V_SZ;
    float* o2   = bias + BI_SZ;
    float* wtab = o2 + O2_SZ;
    int*   iyb  = (int*)(wtab + L_SEQ * 4);
    int*   ixb  = iyb + L_SEQ * 4;

    // 1. interp tables (784 positions)
    interp_tab_kernel<<<(L_SEQ + 255) / 256, 256, 0, stream>>>(wtab, iyb, ixb);

    // 2. bias[h][o][p] (8 * 784 * 784)
    {
        int total = NH * L_SEQ * L_SEQ;
        bias_kernel<<<(total + 255) / 256, 256, 0, stream>>>(table, wtab, iyb, ixb, bias);
    }

    // 3. qkv GEMM + scatter
    {
        dim3 grid(12544 / 64, EDIM / 64);  // (196, 24)
        qkv_gemm_kernel<<<grid, 256, 0, stream>>>(x, Wqkv, qb, kb, vb);
    }

    // 4. attention
    attn_kernel<<<B_SZ * NH * QTILES, 256, 0, stream>>>(qb, kb, vb, bias, o2);

    // 5. output projection
    {
        dim3 grid(12544 / 64, DIM / 64);  // (196, 6)
        proj_gemm_kernel<<<grid, 256, 0, stream>>>(o2, Wproj, bproj, out);
    }
}

// Round 3
// 949.342 us; speedup vs baseline: 2.7783x; 2.7783x over previous
//
#include <hip/hip_runtime.h>
#include <cstddef>

#define L_SEQ 784
#define DIM 384
#define B_SZ 16
#define NH 8
#define QKD 32
#define VD 128
#define EDIM 1536   // NH*(2*QKD+VD)
#define RESN 25
#define NPTS 625    // RESN*RESN
#define ODIM 1024   // NH*VD
#define NQT 13      // ceil(784/64) q-tiles
#define NKT 13      // ceil(784/64) k-tiles

// ---------------------------------------------------------------------------
// cubic interpolation weight (a = -0.75), matches reference _cubic_weight
// ---------------------------------------------------------------------------
__device__ __forceinline__ float cubic_w(float x) {
    float ax = fabsf(x);
    const float a = -0.75f;
    float w1 = ((a + 2.0f) * ax - (a + 3.0f)) * ax * ax + 1.0f;
    float w2 = a * (((ax - 5.0f) * ax + 8.0f) * ax - 4.0f);
    return ax <= 1.0f ? w1 : (ax < 2.0f ? w2 : 0.0f);
}

__global__ void interp_tab_kernel(float* __restrict__ wtab,
                                  int* __restrict__ iyb,
                                  int* __restrict__ ixb) {
    int o = blockIdx.x * blockDim.x + threadIdx.x;
    if (o >= L_SEQ) return;
    const float scale = 625.0f / 784.0f;
    float src = ((float)o + 0.5f) * scale - 0.5f;
    float f = floorf(src);
    float t = src - f;
    int fi = (int)f;
    float w[4];
    w[0] = cubic_w(t + 1.0f);
    w[1] = cubic_w(t);
    w[2] = cubic_w(1.0f - t);
    w[3] = cubic_w(2.0f - t);
#pragma unroll
    for (int j = 0; j < 4; ++j) {
        int idx = fi - 1 + j;
        idx = idx < 0 ? 0 : (idx > NPTS - 1 ? NPTS - 1 : idx);
        wtab[o * 4 + j] = w[j];
        iyb[o * 4 + j] = idx / RESN;
        ixb[o * 4 + j] = idx % RESN;
    }
}

// bias[h][o][p] via 4x4 stencil (interp matrix has 4 nonzeros/row)
__global__ __launch_bounds__(256) void bias_kernel(const float* __restrict__ table,
                                                   const float* __restrict__ wtab,
                                                   const int* __restrict__ iyb,
                                                   const int* __restrict__ ixb,
                                                   float* __restrict__ bias) {
    int idx = blockIdx.x * 256 + threadIdx.x;
    const int total = NH * L_SEQ * L_SEQ;
    if (idx >= total) return;
    int h = idx / (L_SEQ * L_SEQ);
    int rem = idx - h * (L_SEQ * L_SEQ);
    int o = rem / L_SEQ;
    int p = rem - o * L_SEQ;
    const float* th = table + h * NPTS;
    float wo[4], wp[4];
    int oy[4], ox[4], py[4], px[4];
#pragma unroll
    for (int a = 0; a < 4; ++a) {
        wo[a] = wtab[o * 4 + a]; oy[a] = iyb[o * 4 + a]; ox[a] = ixb[o * 4 + a];
        wp[a] = wtab[p * 4 + a]; py[a] = iyb[p * 4 + a]; px[a] = ixb[p * 4 + a];
    }
    float s = 0.0f;
#pragma unroll
    for (int a = 0; a < 4; ++a) {
#pragma unroll
        for (int b = 0; b < 4; ++b) {
            int dy = abs(oy[a] - py[b]);
            int dx = abs(ox[a] - px[b]);
            s += wo[a] * wp[b] * th[dy * RESN + dx];
        }
    }
    bias[idx] = s;
}

// ---------------------------------------------------------------------------
// qkv GEMM: C[m,n] = sum_k X[m,k] * Wqkv[n,k];  M=12544, N=1536, K=384
// ---------------------------------------------------------------------------
__global__ __launch_bounds__(256) void qkv_gemm_kernel(const float* __restrict__ X,
                                                       const float* __restrict__ W,
                                                       float* __restrict__ qb,
                                                       float* __restrict__ kb,
                                                       float* __restrict__ vb) {
    __shared__ float As[16][68];
    __shared__ float Bs[16][68];
    int tid = threadIdx.x;
    int m0 = blockIdx.x * 64;
    int n0 = blockIdx.y * 64;
    int tx = tid & 15, ty = tid >> 4;
    int lr = tid >> 2;
    int lk = (tid & 3) * 4;
    float acc[4][4] = {};
    for (int k0 = 0; k0 < DIM; k0 += 16) {
        float4 av = *(const float4*)(X + (size_t)(m0 + lr) * DIM + k0 + lk);
        float4 bv = *(const float4*)(W + (size_t)(n0 + lr) * DIM + k0 + lk);
        __syncthreads();
        As[lk + 0][lr] = av.x; As[lk + 1][lr] = av.y; As[lk + 2][lr] = av.z; As[lk + 3][lr] = av.w;
        Bs[lk + 0][lr] = bv.x; Bs[lk + 1][lr] = bv.y; Bs[lk + 2][lr] = bv.z; Bs[lk + 3][lr] = bv.w;
        __syncthreads();
#pragma unroll
        for (int kk = 0; kk < 16; ++kk) {
            float4 a = *(const float4*)&As[kk][ty * 4];
            float4 b = *(const float4*)&Bs[kk][tx * 4];
            acc[0][0] += a.x * b.x; acc[0][1] += a.x * b.y; acc[0][2] += a.x * b.z; acc[0][3] += a.x * b.w;
            acc[1][0] += a.y * b.x; acc[1][1] += a.y * b.y; acc[1][2] += a.y * b.z; acc[1][3] += a.y * b.w;
            acc[2][0] += a.z * b.x; acc[2][1] += a.z * b.y; acc[2][2] += a.z * b.z; acc[2][3] += a.z * b.w;
            acc[3][0] += a.w * b.x; acc[3][1] += a.w * b.y; acc[3][2] += a.w * b.z; acc[3][3] += a.w * b.w;
        }
    }
#pragma unroll
    for (int i = 0; i < 4; ++i) {
        int m = m0 + ty * 4 + i;
        int bidx = m / L_SEQ;
        int l = m - bidx * L_SEQ;
#pragma unroll
        for (int j = 0; j < 4; ++j) {
            int n = n0 + tx * 4 + j;
            int head = n / 192;
            int rr = n - head * 192;
            size_t bh = (size_t)bidx * NH + head;
            float val = acc[i][j];
            if (rr < QKD) {
                qb[(bh * L_SEQ + l) * QKD + rr] = val;
            } else if (rr < 2 * QKD) {
                kb[(bh * L_SEQ + l) * QKD + (rr - QKD)] = val;
            } else {
                vb[(bh * L_SEQ + l) * VD + (rr - 2 * QKD)] = val;
            }
        }
    }
}

// ---------------------------------------------------------------------------
// flash attention: block = (b, h, 64-row q-tile); k-tiles of 64 staged in LDS.
// Q/K stored d-major (transposed) in LDS for conflict-free rank-1 updates.
// Scores in registers (4x4/thread), online softmax, P via LDS, PV from LDS.
// ---------------------------------------------------------------------------
__global__ __launch_bounds__(256) void flash_attn_kernel(const float* __restrict__ qg,
                                                         const float* __restrict__ kg,
                                                         const float* __restrict__ vg,
                                                         const float* __restrict__ bias,
                                                         float* __restrict__ o2) {
    __shared__ float Qt[QKD][64];    // 8 KB, [d][row]
    __shared__ float Kt[QKD][64];    // 8 KB, [d][row]
    __shared__ float Vs[64][VD];     // 32 KB
    __shared__ float Ps[64][68];     // 17 KB (+4 pad)

    const int tid = threadIdx.x;
    const int bh = blockIdx.x / NQT;
    const int qt = blockIdx.x - bh * NQT;
    const int b = bh >> 3, h = bh & 7;
    const int q0 = qt * 64;
    const int tx = tid & 15, ty = tid >> 4;

    const float* qp = qg + (size_t)bh * L_SEQ * QKD;
    const float* kp = kg + (size_t)bh * L_SEQ * QKD;
    const float* vp = vg + (size_t)bh * L_SEQ * VD;

    // stage Q transposed (once per block)
    {
        int lr = tid & 63;
        int d0 = (tid >> 6) * 8;
        int gq = q0 + lr; if (gq > L_SEQ - 1) gq = L_SEQ - 1;
        const float* src = qp + (size_t)gq * QKD + d0;
        float4 a = *(const float4*)src;
        float4 c = *(const float4*)(src + 4);
        Qt[d0 + 0][lr] = a.x; Qt[d0 + 1][lr] = a.y; Qt[d0 + 2][lr] = a.z; Qt[d0 + 3][lr] = a.w;
        Qt[d0 + 4][lr] = c.x; Qt[d0 + 5][lr] = c.y; Qt[d0 + 6][lr] = c.z; Qt[d0 + 7][lr] = c.w;
    }

    int gqr[4];
#pragma unroll
    for (int i = 0; i < 4; ++i) {
        int g = q0 + 4 * ty + i;
        gqr[i] = g > L_SEQ - 1 ? L_SEQ - 1 : g;
    }

    float m_i[4], l_i[4], o[4][8];
#pragma unroll
    for (int i = 0; i < 4; ++i) {
        m_i[i] = -1e30f; l_i[i] = 0.0f;
#pragma unroll
        for (int j = 0; j < 8; ++j) o[i][j] = 0.0f;
    }

    const float scale = 0.17677669529663687f;  // 32^-0.5

    for (int kt = 0; kt < NKT; ++kt) {
        const int k0 = kt * 64;
        __syncthreads();  // protect Kt/Vs/Ps from previous iteration's readers
        // stage K transposed
        {
            int lr = tid & 63;
            int d0 = (tid >> 6) * 8;
            int gk = k0 + lr; if (gk > L_SEQ - 1) gk = L_SEQ - 1;
            const float* src = kp + (size_t)gk * QKD + d0;
            float4 a = *(const float4*)src;
            float4 c = *(const float4*)(src + 4);
            Kt[d0 + 0][lr] = a.x; Kt[d0 + 1][lr] = a.y; Kt[d0 + 2][lr] = a.z; Kt[d0 + 3][lr] = a.w;
            Kt[d0 + 4][lr] = c.x; Kt[d0 + 5][lr] = c.y; Kt[d0 + 6][lr] = c.z; Kt[d0 + 7][lr] = c.w;
        }
        // stage V: 64 rows x 128 cols = 2048 float4s, 8 per thread
#pragma unroll
        for (int t = 0; t < 8; ++t) {
            int idx = tid + t * 256;      // 0..2047
            int lr = idx >> 5;            // 0..63
            int c4 = (idx & 31) * 4;      // 0..124
            int gk = k0 + lr; if (gk > L_SEQ - 1) gk = L_SEQ - 1;
            *(float4*)&Vs[lr][c4] = *(const float4*)(vp + (size_t)gk * VD + c4);
        }
        __syncthreads();

        // ---- scores: rank-1 updates over d ----
        float s[4][4] = {};
#pragma unroll
        for (int d = 0; d < QKD; ++d) {
            float4 qv = *(const float4*)&Qt[d][4 * ty];
            float4 kv = *(const float4*)&Kt[d][4 * tx];
            s[0][0] += qv.x * kv.x; s[0][1] += qv.x * kv.y; s[0][2] += qv.x * kv.z; s[0][3] += qv.x * kv.w;
            s[1][0] += qv.y * kv.x; s[1][1] += qv.y * kv.y; s[1][2] += qv.y * kv.z; s[1][3] += qv.y * kv.w;
            s[2][0] += qv.z * kv.x; s[2][1] += qv.z * kv.y; s[2][2] += qv.z * kv.z; s[2][3] += qv.z * kv.w;
            s[3][0] += qv.w * kv.x; s[3][1] += qv.w * kv.y; s[3][2] += qv.w * kv.z; s[3][3] += qv.w * kv.w;
        }
        // scale + bias
#pragma unroll
        for (int i = 0; i < 4; ++i) {
            const float* bprow = bias + ((size_t)h * L_SEQ + gqr[i]) * L_SEQ;
            float4 bv = *(const float4*)(bprow + k0 + 4 * tx);
            s[i][0] = s[i][0] * scale + bv.x;
            s[i][1] = s[i][1] * scale + bv.y;
            s[i][2] = s[i][2] * scale + bv.z;
            s[i][3] = s[i][3] * scale + bv.w;
        }
        if (kt == NKT - 1) {
#pragma unroll
            for (int j = 0; j < 4; ++j) {
                if (k0 + 4 * tx + j >= L_SEQ) {
                    s[0][j] = -1e30f; s[1][j] = -1e30f; s[2][j] = -1e30f; s[3][j] = -1e30f;
                }
            }
        }
        // ---- online softmax (16-lane groups share a q-row) ----
#pragma unroll
        for (int i = 0; i < 4; ++i) {
            float mx = fmaxf(fmaxf(s[i][0], s[i][1]), fmaxf(s[i][2], s[i][3]));
            mx = fmaxf(mx, __shfl_xor(mx, 1));
            mx = fmaxf(mx, __shfl_xor(mx, 2));
            mx = fmaxf(mx, __shfl_xor(mx, 4));
            mx = fmaxf(mx, __shfl_xor(mx, 8));
            float mn = fmaxf(m_i[i], mx);
            float p0 = __expf(s[i][0] - mn);
            float p1 = __expf(s[i][1] - mn);
            float p2 = __expf(s[i][2] - mn);
            float p3 = __expf(s[i][3] - mn);
            float ls = p0 + p1 + p2 + p3;
            ls += __shfl_xor(ls, 1);
            ls += __shfl_xor(ls, 2);
            ls += __shfl_xor(ls, 4);
            ls += __shfl_xor(ls, 8);
            float alpha = __expf(m_i[i] - mn);
            m_i[i] = mn;
            l_i[i] = l_i[i] * alpha + ls;
#pragma unroll
            for (int j = 0; j < 8; ++j) o[i][j] *= alpha;
            float4 pw = make_float4(p0, p1, p2, p3);
            *(float4*)&Ps[4 * ty + i][4 * tx] = pw;
        }
        __syncthreads();

        // ---- PV from LDS ----
#pragma unroll 2
        for (int kk = 0; kk < 64; kk += 4) {
            float4 pr[4];
#pragma unroll
            for (int i = 0; i < 4; ++i) pr[i] = *(const float4*)&Ps[4 * ty + i][kk];
#pragma unroll
            for (int t = 0; t < 4; ++t) {
                float4 va = *(const float4*)&Vs[kk + t][4 * tx];
                float4 vb2 = *(const float4*)&Vs[kk + t][64 + 4 * tx];
#pragma unroll
                for (int i = 0; i < 4; ++i) {
                    float pc = (t == 0) ? pr[i].x : (t == 1) ? pr[i].y : (t == 2) ? pr[i].z : pr[i].w;
                    o[i][0] += pc * va.x;  o[i][1] += pc * va.y;
                    o[i][2] += pc * va.z;  o[i][3] += pc * va.w;
                    o[i][4] += pc * vb2.x; o[i][5] += pc * vb2.y;
                    o[i][6] += pc * vb2.z; o[i][7] += pc * vb2.w;
                }
            }
        }
    }

    // epilogue: normalize + store
#pragma unroll
    for (int i = 0; i < 4; ++i) {
        int gq = q0 + 4 * ty + i;
        if (gq >= L_SEQ) continue;
        float inv = 1.0f / l_i[i];
        float* dst = o2 + ((size_t)b * L_SEQ + gq) * ODIM + h * VD;
        float4 r0 = make_float4(o[i][0] * inv, o[i][1] * inv, o[i][2] * inv, o[i][3] * inv);
        float4 r1 = make_float4(o[i][4] * inv, o[i][5] * inv, o[i][6] * inv, o[i][7] * inv);
        *(float4*)(dst + 4 * tx) = r0;
        *(float4*)(dst + 64 + 4 * tx) = r1;
    }
}

// ---------------------------------------------------------------------------
// output projection: out[m,n] = sum_e o2[m,e]*Wproj[n,e] + bproj[n]
// ---------------------------------------------------------------------------
__global__ __launch_bounds__(256) void proj_gemm_kernel(const float* __restrict__ X,
                                                        const float* __restrict__ W,
                                                        const float* __restrict__ bproj,
                                                        float* __restrict__ out) {
    __shared__ float As[16][68];
    __shared__ float Bs[16][68];
    int tid = threadIdx.x;
    int m0 = blockIdx.x * 64;
    int n0 = blockIdx.y * 64;
    int tx = tid & 15, ty = tid >> 4;
    int lr = tid >> 2;
    int lk = (tid & 3) * 4;
    float acc[4][4] = {};
    for (int k0 = 0; k0 < ODIM; k0 += 16) {
        float4 av = *(const float4*)(X + (size_t)(m0 + lr) * ODIM + k0 + lk);
        float4 bv = *(const float4*)(W + (size_t)(n0 + lr) * ODIM + k0 + lk);
        __syncthreads();
        As[lk + 0][lr] = av.x; As[lk + 1][lr] = av.y; As[lk + 2][lr] = av.z; As[lk + 3][lr] = av.w;
        Bs[lk + 0][lr] = bv.x; Bs[lk + 1][lr] = bv.y; Bs[lk + 2][lr] = bv.z; Bs[lk + 3][lr] = bv.w;
        __syncthreads();
#pragma unroll
        for (int kk = 0; kk < 16; ++kk) {
            float4 a = *(const float4*)&As[kk][ty * 4];
            float4 b = *(const float4*)&Bs[kk][tx * 4];
            acc[0][0] += a.x * b.x; acc[0][1] += a.x * b.y; acc[0][2] += a.x * b.z; acc[0][3] += a.x * b.w;
            acc[1][0] += a.y * b.x; acc[1][1] += a.y * b.y; acc[1][2] += a.y * b.z; acc[1][3] += a.y * b.w;
            acc[2][0] += a.z * b.x; acc[2][1] += a.z * b.y; acc[2][2] += a.z * b.z; acc[2][3] += a.z * b.w;
            acc[3][0] += a.w * b.x; acc[3][1] += a.w * b.y; acc[3][2] += a.w * b.z; acc[3][3] += a.w * b.w;
        }
    }
#pragma unroll
    for (int i = 0; i < 4; ++i) {
        int m = m0 + ty * 4 + i;
#pragma unroll
        for (int j = 0; j < 4; ++j) {
            int n = n0 + tx * 4 + j;
            out[(size_t)m * DIM + n] = acc[i][j] + bproj[n];
        }
    }
}

// ---------------------------------------------------------------------------
// launch
// ---------------------------------------------------------------------------
extern "C" void kernel_launch(void* const* d_in, const int* in_sizes, int n_in,
                              void* d_out, int out_size, void* d_ws, size_t ws_size,
                              hipStream_t stream) {
    const float* x      = (const float*)d_in[0];  // (16,784,384)
    const float* Wqkv   = (const float*)d_in[1];  // (1536,384)
    const float* Wproj  = (const float*)d_in[2];  // (384,1024)
    const float* bproj  = (const float*)d_in[3];  // (384,)
    const float* table  = (const float*)d_in[4];  // (8,625)
    float* out = (float*)d_out;

    const size_t QK_SZ = (size_t)B_SZ * NH * L_SEQ * QKD;
    const size_t V_SZ  = (size_t)B_SZ * NH * L_SEQ * VD;
    const size_t BI_SZ = (size_t)NH * L_SEQ * L_SEQ;
    const size_t O2_SZ = (size_t)B_SZ * L_SEQ * ODIM;

    float* ws   = (float*)d_ws;
    float* qb   = ws;
    float* kb   = qb + QK_SZ;
    float* vb   = kb + QK_SZ;
    float* bias = vb + V_SZ;
    float* o2   = bias + BI_SZ;
    float* wtab = o2 + O2_SZ;
    int*   iyb  = (int*)(wtab + L_SEQ * 4);
    int*   ixb  = iyb + L_SEQ * 4;

    interp_tab_kernel<<<(L_SEQ + 255) / 256, 256, 0, stream>>>(wtab, iyb, ixb);

    {
        int total = NH * L_SEQ * L_SEQ;
        bias_kernel<<<(total + 255) / 256, 256, 0, stream>>>(table, wtab, iyb, ixb, bias);
    }

    {
        dim3 grid(12544 / 64, EDIM / 64);
        qkv_gemm_kernel<<<grid, 256, 0, stream>>>(x, Wqkv, qb, kb, vb);
    }

    flash_attn_kernel<<<B_SZ * NH * NQT, 256, 0, stream>>>(qb, kb, vb, bias, o2);

    {
        dim3 grid(12544 / 64, DIM / 64);
        proj_gemm_kernel<<<grid, 256, 0, stream>>>(o2, Wproj, bproj, out);
    }
}

// Round 5
// 842.351 us; speedup vs baseline: 3.1312x; 1.1270x over previous
//
#include <hip/hip_runtime.h>
#include <cstddef>

#define L_SEQ 784
#define DIM 384
#define B_SZ 16
#define NH 8
#define QKD 32
#define VD 128
#define EDIM 1536   // NH*(2*QKD+VD)
#define RESN 25
#define NPTS 625    // RESN*RESN
#define ODIM 1024   // NH*VD
#define NQT 13      // ceil(784/64) q-tiles
#define NKT 13      // ceil(784/64) k-tiles

typedef short s16x8 __attribute__((ext_vector_type(8)));
typedef float f32x4v __attribute__((ext_vector_type(4)));

__device__ __forceinline__ short f2bf(float f) {
    union { float f; unsigned u; } c; c.f = f;
    unsigned u = c.u;
    return (short)((u + 0x7FFFu + ((u >> 16) & 1u)) >> 16);
}

// ---------------------------------------------------------------------------
// cubic interpolation weight (a = -0.75), matches reference _cubic_weight
// ---------------------------------------------------------------------------
__device__ __forceinline__ float cubic_w(float x) {
    float ax = fabsf(x);
    const float a = -0.75f;
    float w1 = ((a + 2.0f) * ax - (a + 3.0f)) * ax * ax + 1.0f;
    float w2 = a * (((ax - 5.0f) * ax + 8.0f) * ax - 4.0f);
    return ax <= 1.0f ? w1 : (ax < 2.0f ? w2 : 0.0f);
}

__global__ void interp_tab_kernel(float* __restrict__ wtab,
                                  int* __restrict__ iyb,
                                  int* __restrict__ ixb) {
    int o = blockIdx.x * blockDim.x + threadIdx.x;
    if (o >= L_SEQ) return;
    const float scale = 625.0f / 784.0f;
    float src = ((float)o + 0.5f) * scale - 0.5f;
    float f = floorf(src);
    float t = src - f;
    int fi = (int)f;
    float w[4];
    w[0] = cubic_w(t + 1.0f);
    w[1] = cubic_w(t);
    w[2] = cubic_w(1.0f - t);
    w[3] = cubic_w(2.0f - t);
#pragma unroll
    for (int j = 0; j < 4; ++j) {
        int idx = fi - 1 + j;
        idx = idx < 0 ? 0 : (idx > NPTS - 1 ? NPTS - 1 : idx);
        wtab[o * 4 + j] = w[j];
        iyb[o * 4 + j] = idx / RESN;
        ixb[o * 4 + j] = idx % RESN;
    }
}

// bias[h][o][p] via 4x4 stencil (interp matrix has 4 nonzeros/row)
__global__ __launch_bounds__(256) void bias_kernel(const float* __restrict__ table,
                                                   const float* __restrict__ wtab,
                                                   const int* __restrict__ iyb,
                                                   const int* __restrict__ ixb,
                                                   float* __restrict__ bias) {
    int idx = blockIdx.x * 256 + threadIdx.x;
    const int total = NH * L_SEQ * L_SEQ;
    if (idx >= total) return;
    int h = idx / (L_SEQ * L_SEQ);
    int rem = idx - h * (L_SEQ * L_SEQ);
    int o = rem / L_SEQ;
    int p = rem - o * L_SEQ;
    const float* th = table + h * NPTS;
    float wo[4], wp[4];
    int oy[4], ox[4], py[4], px[4];
#pragma unroll
    for (int a = 0; a < 4; ++a) {
        wo[a] = wtab[o * 4 + a]; oy[a] = iyb[o * 4 + a]; ox[a] = ixb[o * 4 + a];
        wp[a] = wtab[p * 4 + a]; py[a] = iyb[p * 4 + a]; px[a] = ixb[p * 4 + a];
    }
    float s = 0.0f;
#pragma unroll
    for (int a = 0; a < 4; ++a) {
#pragma unroll
        for (int b = 0; b < 4; ++b) {
            int dy = abs(oy[a] - py[b]);
            int dx = abs(ox[a] - px[b]);
            s += wo[a] * wp[b] * th[dy * RESN + dx];
        }
    }
    bias[idx] = s;
}

// ---------------------------------------------------------------------------
// qkv GEMM: C[m,n] = sum_k X[m,k] * Wqkv[n,k];  M=12544, N=1536, K=384
// ---------------------------------------------------------------------------
__global__ __launch_bounds__(256) void qkv_gemm_kernel(const float* __restrict__ X,
                                                       const float* __restrict__ W,
                                                       float* __restrict__ qb,
                                                       float* __restrict__ kb,
                                                       float* __restrict__ vb) {
    __shared__ float As[16][68];
    __shared__ float Bs[16][68];
    int tid = threadIdx.x;
    int m0 = blockIdx.x * 64;
    int n0 = blockIdx.y * 64;
    int tx = tid & 15, ty = tid >> 4;
    int lr = tid >> 2;
    int lk = (tid & 3) * 4;
    float acc[4][4] = {};
    for (int k0 = 0; k0 < DIM; k0 += 16) {
        float4 av = *(const float4*)(X + (size_t)(m0 + lr) * DIM + k0 + lk);
        float4 bv = *(const float4*)(W + (size_t)(n0 + lr) * DIM + k0 + lk);
        __syncthreads();
        As[lk + 0][lr] = av.x; As[lk + 1][lr] = av.y; As[lk + 2][lr] = av.z; As[lk + 3][lr] = av.w;
        Bs[lk + 0][lr] = bv.x; Bs[lk + 1][lr] = bv.y; Bs[lk + 2][lr] = bv.z; Bs[lk + 3][lr] = bv.w;
        __syncthreads();
#pragma unroll
        for (int kk = 0; kk < 16; ++kk) {
            float4 a = *(const float4*)&As[kk][ty * 4];
            float4 b = *(const float4*)&Bs[kk][tx * 4];
            acc[0][0] += a.x * b.x; acc[0][1] += a.x * b.y; acc[0][2] += a.x * b.z; acc[0][3] += a.x * b.w;
            acc[1][0] += a.y * b.x; acc[1][1] += a.y * b.y; acc[1][2] += a.y * b.z; acc[1][3] += a.y * b.w;
            acc[2][0] += a.z * b.x; acc[2][1] += a.z * b.y; acc[2][2] += a.z * b.z; acc[2][3] += a.z * b.w;
            acc[3][0] += a.w * b.x; acc[3][1] += a.w * b.y; acc[3][2] += a.w * b.z; acc[3][3] += a.w * b.w;
        }
    }
#pragma unroll
    for (int i = 0; i < 4; ++i) {
        int m = m0 + ty * 4 + i;
        int bidx = m / L_SEQ;
        int l = m - bidx * L_SEQ;
#pragma unroll
        for (int j = 0; j < 4; ++j) {
            int n = n0 + tx * 4 + j;
            int head = n / 192;
            int rr = n - head * 192;
            size_t bh = (size_t)bidx * NH + head;
            float val = acc[i][j];
            if (rr < QKD) {
                qb[(bh * L_SEQ + l) * QKD + rr] = val;
            } else if (rr < 2 * QKD) {
                kb[(bh * L_SEQ + l) * QKD + (rr - QKD)] = val;
            } else {
                vb[(bh * L_SEQ + l) * VD + (rr - 2 * QKD)] = val;
            }
        }
    }
}

// ---------------------------------------------------------------------------
// Hybrid flash attention (bisection): MFMA QK^T + C-layout softmax (round-4
// code), P handed to LDS in fp32, PV in fp32 VALU (round-3 verbatim code).
// Per-row alpha/l handed across thread mappings via LDS.
// ---------------------------------------------------------------------------
__global__ __launch_bounds__(256, 2) void flash_attn_hybrid(const float* __restrict__ qg,
                                                            const float* __restrict__ kg,
                                                            const float* __restrict__ vg,
                                                            const float* __restrict__ bias,
                                                            float* __restrict__ o2) {
    __shared__ short Qs[64][40];     // bf16 Q tile, pre-scaled
    __shared__ short Ks[64][40];     // bf16 K tile
    __shared__ float Vs[64][VD];     // fp32 V tile (round-3 layout)
    __shared__ float Psf[64][68];    // fp32 P tile (+4 pad)
    __shared__ float alpha_s[64];
    __shared__ float l_s[64];

    const int tid = threadIdx.x;
    const int wv = tid >> 6;
    const int lane = tid & 63;
    const int quad = lane >> 4;
    const int l15 = lane & 15;
    const int tx = tid & 15, ty = tid >> 4;   // PV-side mapping (round 3)

    const int bh = blockIdx.x / NQT;
    const int qt = blockIdx.x - bh * NQT;
    const int b = bh >> 3, h = bh & 7;
    const int q0 = qt * 64;

    const float* qp = qg + (size_t)bh * L_SEQ * QKD;
    const float* kp = kg + (size_t)bh * L_SEQ * QKD;
    const float* vp = vg + (size_t)bh * L_SEQ * VD;
    const float* bbase = bias + (size_t)h * L_SEQ * L_SEQ;

    const float scale = 0.17677669529663687f;  // 32^-0.5, folded into Q

    // ---- stage Q (scaled, bf16) once ----
    {
        int row = tid >> 2, seg = tid & 3;
        int gq = q0 + row; if (gq > L_SEQ - 1) gq = L_SEQ - 1;
        const float* src = qp + (size_t)gq * QKD + seg * 8;
        float4 a = *(const float4*)src;
        float4 c = *(const float4*)(src + 4);
        s16x8 w;
        w[0] = f2bf(a.x * scale); w[1] = f2bf(a.y * scale);
        w[2] = f2bf(a.z * scale); w[3] = f2bf(a.w * scale);
        w[4] = f2bf(c.x * scale); w[5] = f2bf(c.y * scale);
        w[6] = f2bf(c.z * scale); w[7] = f2bf(c.w * scale);
        *(s16x8*)&Qs[row][seg * 8] = w;
    }
    __syncthreads();
    s16x8 qfrag = *(const s16x8*)&Qs[wv * 16 + l15][quad * 8];

    int gqr[4];
#pragma unroll
    for (int r = 0; r < 4; ++r) {
        int g = q0 + wv * 16 + quad * 4 + r;
        gqr[r] = g > L_SEQ - 1 ? L_SEQ - 1 : g;
    }

    // softmax state (C-layout lanes)
    float m_i[4] = {-1e30f, -1e30f, -1e30f, -1e30f};
    float l_i[4] = {0.f, 0.f, 0.f, 0.f};
    // PV accumulators (round-3 mapping: rows 4*ty+i, cols 4*tx & 64+4*tx)
    float o[4][8] = {};

    for (int kt = 0; kt < NKT; ++kt) {
        const int k0 = kt * 64;
        __syncthreads();  // prior tile's readers done
        // ---- stage K (bf16, round-4 code) ----
        {
            int row = tid >> 2, seg = tid & 3;
            int gk = k0 + row; if (gk > L_SEQ - 1) gk = L_SEQ - 1;
            const float* src = kp + (size_t)gk * QKD + seg * 8;
            float4 a = *(const float4*)src;
            float4 c = *(const float4*)(src + 4);
            s16x8 w;
            w[0] = f2bf(a.x); w[1] = f2bf(a.y); w[2] = f2bf(a.z); w[3] = f2bf(a.w);
            w[4] = f2bf(c.x); w[5] = f2bf(c.y); w[6] = f2bf(c.z); w[7] = f2bf(c.w);
            *(s16x8*)&Ks[row][seg * 8] = w;
        }
        // ---- stage V fp32 (round-3 verbatim) ----
#pragma unroll
        for (int t = 0; t < 8; ++t) {
            int idx = tid + t * 256;      // 0..2047
            int lr = idx >> 5;            // 0..63
            int c4 = (idx & 31) * 4;      // 0..124
            int gk = k0 + lr; if (gk > L_SEQ - 1) gk = L_SEQ - 1;
            *(float4*)&Vs[lr][c4] = *(const float4*)(vp + (size_t)gk * VD + c4);
        }
        __syncthreads();

        // ---- QK^T: 4 MFMAs (16 q-rows x 64 k-cols per wave) ----
        f32x4v s[4];
#pragma unroll
        for (int t = 0; t < 4; ++t) {
            s16x8 kf = *(const s16x8*)&Ks[t * 16 + l15][quad * 8];
            f32x4v z; z[0] = 0.f; z[1] = 0.f; z[2] = 0.f; z[3] = 0.f;
            s[t] = __builtin_amdgcn_mfma_f32_16x16x32_bf16(qfrag, kf, z, 0, 0, 0);
        }
        // ---- + bias (C-layout gather) ----
#pragma unroll
        for (int t = 0; t < 4; ++t) {
            int col = k0 + t * 16 + l15;
            int bc = col > L_SEQ - 1 ? L_SEQ - 1 : col;
#pragma unroll
            for (int r = 0; r < 4; ++r)
                s[t][r] += bbase[(size_t)gqr[r] * L_SEQ + bc];
        }
        // ---- k-tail mask ----
        if (kt == NKT - 1) {
#pragma unroll
            for (int t = 0; t < 4; ++t) {
                if (k0 + t * 16 + l15 >= L_SEQ) {
                    s[t][0] = -1e30f; s[t][1] = -1e30f; s[t][2] = -1e30f; s[t][3] = -1e30f;
                }
            }
        }
        // ---- online softmax (C-layout rows; 16-lane quad groups) ----
#pragma unroll
        for (int r = 0; r < 4; ++r) {
            float mx = fmaxf(fmaxf(s[0][r], s[1][r]), fmaxf(s[2][r], s[3][r]));
            mx = fmaxf(mx, __shfl_xor(mx, 1, 16));
            mx = fmaxf(mx, __shfl_xor(mx, 2, 16));
            mx = fmaxf(mx, __shfl_xor(mx, 4, 16));
            mx = fmaxf(mx, __shfl_xor(mx, 8, 16));
            float mn = fmaxf(m_i[r], mx);
            float ls = 0.f;
#pragma unroll
            for (int t = 0; t < 4; ++t) {
                float p = __expf(s[t][r] - mn);
                s[t][r] = p;
                ls += p;
            }
            ls += __shfl_xor(ls, 1, 16);
            ls += __shfl_xor(ls, 2, 16);
            ls += __shfl_xor(ls, 4, 16);
            ls += __shfl_xor(ls, 8, 16);
            float alpha = __expf(m_i[r] - mn);
            m_i[r] = mn;
            l_i[r] = l_i[r] * alpha + ls;
            // P (fp32) to LDS, C-layout addressing
#pragma unroll
            for (int t = 0; t < 4; ++t)
                Psf[wv * 16 + quad * 4 + r][t * 16 + l15] = s[t][r];
            if (l15 == 0) alpha_s[wv * 16 + quad * 4 + r] = alpha;
        }
        __syncthreads();  // P/alpha visible to PV threads

        // ---- PV fp32 (round-3 verbatim) ----
#pragma unroll
        for (int i = 0; i < 4; ++i) {
            float a = alpha_s[4 * ty + i];
#pragma unroll
            for (int j = 0; j < 8; ++j) o[i][j] *= a;
        }
#pragma unroll 2
        for (int kk = 0; kk < 64; kk += 4) {
            float4 pr[4];
#pragma unroll
            for (int i = 0; i < 4; ++i) pr[i] = *(const float4*)&Psf[4 * ty + i][kk];
#pragma unroll
            for (int t = 0; t < 4; ++t) {
                float4 va = *(const float4*)&Vs[kk + t][4 * tx];
                float4 vb2 = *(const float4*)&Vs[kk + t][64 + 4 * tx];
#pragma unroll
                for (int i = 0; i < 4; ++i) {
                    float pc = (t == 0) ? pr[i].x : (t == 1) ? pr[i].y : (t == 2) ? pr[i].z : pr[i].w;
                    o[i][0] += pc * va.x;  o[i][1] += pc * va.y;
                    o[i][2] += pc * va.z;  o[i][3] += pc * va.w;
                    o[i][4] += pc * vb2.x; o[i][5] += pc * vb2.y;
                    o[i][6] += pc * vb2.z; o[i][7] += pc * vb2.w;
                }
            }
        }
    }

    // hand l_i to PV threads
#pragma unroll
    for (int r = 0; r < 4; ++r)
        if (l15 == 0) l_s[wv * 16 + quad * 4 + r] = l_i[r];
    __syncthreads();

    // ---- epilogue (round-3 mapping) ----
#pragma unroll
    for (int i = 0; i < 4; ++i) {
        int gq = q0 + 4 * ty + i;
        if (gq >= L_SEQ) continue;
        float inv = 1.0f / l_s[4 * ty + i];
        float* dst = o2 + ((size_t)b * L_SEQ + gq) * ODIM + h * VD;
        float4 r0 = make_float4(o[i][0] * inv, o[i][1] * inv, o[i][2] * inv, o[i][3] * inv);
        float4 r1 = make_float4(o[i][4] * inv, o[i][5] * inv, o[i][6] * inv, o[i][7] * inv);
        *(float4*)(dst + 4 * tx) = r0;
        *(float4*)(dst + 64 + 4 * tx) = r1;
    }
}

// ---------------------------------------------------------------------------
// output projection: out[m,n] = sum_e o2[m,e]*Wproj[n,e] + bproj[n]
// ---------------------------------------------------------------------------
__global__ __launch_bounds__(256) void proj_gemm_kernel(const float* __restrict__ X,
                                                        const float* __restrict__ W,
                                                        const float* __restrict__ bproj,
                                                        float* __restrict__ out) {
    __shared__ float As[16][68];
    __shared__ float Bs[16][68];
    int tid = threadIdx.x;
    int m0 = blockIdx.x * 64;
    int n0 = blockIdx.y * 64;
    int tx = tid & 15, ty = tid >> 4;
    int lr = tid >> 2;
    int lk = (tid & 3) * 4;
    float acc[4][4] = {};
    for (int k0 = 0; k0 < ODIM; k0 += 16) {
        float4 av = *(const float4*)(X + (size_t)(m0 + lr) * ODIM + k0 + lk);
        float4 bv = *(const float4*)(W + (size_t)(n0 + lr) * ODIM + k0 + lk);
        __syncthreads();
        As[lk + 0][lr] = av.x; As[lk + 1][lr] = av.y; As[lk + 2][lr] = av.z; As[lk + 3][lr] = av.w;
        Bs[lk + 0][lr] = bv.x; Bs[lk + 1][lr] = bv.y; Bs[lk + 2][lr] = bv.z; Bs[lk + 3][lr] = bv.w;
        __syncthreads();
#pragma unroll
        for (int kk = 0; kk < 16; ++kk) {
            float4 a = *(const float4*)&As[kk][ty * 4];
            float4 b = *(const float4*)&Bs[kk][tx * 4];
            acc[0][0] += a.x * b.x; acc[0][1] += a.x * b.y; acc[0][2] += a.x * b.z; acc[0][3] += a.x * b.w;
            acc[1][0] += a.y * b.x; acc[1][1] += a.y * b.y; acc[1][2] += a.y * b.z; acc[1][3] += a.y * b.w;
            acc[2][0] += a.z * b.x; acc[2][1] += a.z * b.y; acc[2][2] += a.z * b.z; acc[2][3] += a.z * b.w;
            acc[3][0] += a.w * b.x; acc[3][1] += a.w * b.y; acc[3][2] += a.w * b.z; acc[3][3] += a.w * b.w;
        }
    }
#pragma unroll
    for (int i = 0; i < 4; ++i) {
        int m = m0 + ty * 4 + i;
#pragma unroll
        for (int j = 0; j < 4; ++j) {
            int n = n0 + tx * 4 + j;
            out[(size_t)m * DIM + n] = acc[i][j] + bproj[n];
        }
    }
}

// ---------------------------------------------------------------------------
// launch
// ---------------------------------------------------------------------------
extern "C" void kernel_launch(void* const* d_in, const int* in_sizes, int n_in,
                              void* d_out, int out_size, void* d_ws, size_t ws_size,
                              hipStream_t stream) {
    const float* x      = (const float*)d_in[0];  // (16,784,384)
    const float* Wqkv   = (const float*)d_in[1];  // (1536,384)
    const float* Wproj  = (const float*)d_in[2];  // (384,1024)
    const float* bproj  = (const float*)d_in[3];  // (384,)
    const float* table  = (const float*)d_in[4];  // (8,625)
    float* out = (float*)d_out;

    const size_t QK_SZ = (size_t)B_SZ * NH * L_SEQ * QKD;
    const size_t V_SZ  = (size_t)B_SZ * NH * L_SEQ * VD;
    const size_t BI_SZ = (size_t)NH * L_SEQ * L_SEQ;
    const size_t O2_SZ = (size_t)B_SZ * L_SEQ * ODIM;

    float* ws   = (float*)d_ws;
    float* qb   = ws;
    float* kb   = qb + QK_SZ;
    float* vb   = kb + QK_SZ;
    float* bias = vb + V_SZ;
    float* o2   = bias + BI_SZ;
    float* wtab = o2 + O2_SZ;
    int*   iyb  = (int*)(wtab + L_SEQ * 4);
    int*   ixb  = iyb + L_SEQ * 4;

    interp_tab_kernel<<<(L_SEQ + 255) / 256, 256, 0, stream>>>(wtab, iyb, ixb);

    {
        int total = NH * L_SEQ * L_SEQ;
        bias_kernel<<<(total + 255) / 256, 256, 0, stream>>>(table, wtab, iyb, ixb, bias);
    }

    {
        dim3 grid(12544 / 64, EDIM / 64);
        qkv_gemm_kernel<<<grid, 256, 0, stream>>>(x, Wqkv, qb, kb, vb);
    }

    flash_attn_hybrid<<<B_SZ * NH * NQT, 256, 0, stream>>>(qb, kb, vb, bias, o2);

    {
        dim3 grid(12544 / 64, DIM / 64);
        proj_gemm_kernel<<<grid, 256, 0, stream>>>(o2, Wproj, bproj, out);
    }
}

// Round 6
// 476.156 us; speedup vs baseline: 5.5393x; 1.7691x over previous
//
#include <hip/hip_runtime.h>
#include <cstddef>

#define L_SEQ 784
#define DIM 384
#define B_SZ 16
#define NH 8
#define QKD 32
#define VD 128
#define EDIM 1536   // NH*(2*QKD+VD)
#define RESN 25
#define NPTS 625    // RESN*RESN
#define ODIM 1024   // NH*VD
#define NQT 13      // ceil(784/64) q-tiles
#define NKT 13      // ceil(784/64) k-tiles

typedef short s16x8 __attribute__((ext_vector_type(8)));
typedef short s16x4 __attribute__((ext_vector_type(4)));
typedef float f32x4v __attribute__((ext_vector_type(4)));

__device__ __forceinline__ short f2bf(float f) {
    union { float f; unsigned u; } c; c.f = f;
    unsigned u = c.u;
    return (short)((u + 0x7FFFu + ((u >> 16) & 1u)) >> 16);
}

// load an 8-elt bf16 fragment as two b64 reads (rows are 8B-aligned, not 16B)
__device__ __forceinline__ s16x8 ld_frag(const short* p) {
    s16x4 lo = *(const s16x4*)p;
    s16x4 hi = *(const s16x4*)(p + 4);
    s16x8 r;
    r[0] = lo[0]; r[1] = lo[1]; r[2] = lo[2]; r[3] = lo[3];
    r[4] = hi[0]; r[5] = hi[1]; r[6] = hi[2]; r[7] = hi[3];
    return r;
}

__device__ __forceinline__ void st_frag(short* p, s16x8 w) {
    s16x4 lo, hi;
    lo[0] = w[0]; lo[1] = w[1]; lo[2] = w[2]; lo[3] = w[3];
    hi[0] = w[4]; hi[1] = w[5]; hi[2] = w[6]; hi[3] = w[7];
    *(s16x4*)p = lo;
    *(s16x4*)(p + 4) = hi;
}

// ---------------------------------------------------------------------------
// cubic interpolation weight (a = -0.75), matches reference _cubic_weight
// ---------------------------------------------------------------------------
__device__ __forceinline__ float cubic_w(float x) {
    float ax = fabsf(x);
    const float a = -0.75f;
    float w1 = ((a + 2.0f) * ax - (a + 3.0f)) * ax * ax + 1.0f;
    float w2 = a * (((ax - 5.0f) * ax + 8.0f) * ax - 4.0f);
    return ax <= 1.0f ? w1 : (ax < 2.0f ? w2 : 0.0f);
}

__global__ void interp_tab_kernel(float* __restrict__ wtab,
                                  int* __restrict__ iyb,
                                  int* __restrict__ ixb) {
    int o = blockIdx.x * blockDim.x + threadIdx.x;
    if (o >= L_SEQ) return;
    const float scale = 625.0f / 784.0f;
    float src = ((float)o + 0.5f) * scale - 0.5f;
    float f = floorf(src);
    float t = src - f;
    int fi = (int)f;
    float w[4];
    w[0] = cubic_w(t + 1.0f);
    w[1] = cubic_w(t);
    w[2] = cubic_w(1.0f - t);
    w[3] = cubic_w(2.0f - t);
#pragma unroll
    for (int j = 0; j < 4; ++j) {
        int idx = fi - 1 + j;
        idx = idx < 0 ? 0 : (idx > NPTS - 1 ? NPTS - 1 : idx);
        wtab[o * 4 + j] = w[j];
        iyb[o * 4 + j] = idx / RESN;
        ixb[o * 4 + j] = idx % RESN;
    }
}

// bias[h][o][p] via 4x4 stencil (interp matrix has 4 nonzeros/row)
__global__ __launch_bounds__(256) void bias_kernel(const float* __restrict__ table,
                                                   const float* __restrict__ wtab,
                                                   const int* __restrict__ iyb,
                                                   const int* __restrict__ ixb,
                                                   float* __restrict__ bias) {
    int idx = blockIdx.x * 256 + threadIdx.x;
    const int total = NH * L_SEQ * L_SEQ;
    if (idx >= total) return;
    int h = idx / (L_SEQ * L_SEQ);
    int rem = idx - h * (L_SEQ * L_SEQ);
    int o = rem / L_SEQ;
    int p = rem - o * L_SEQ;
    const float* th = table + h * NPTS;
    float wo[4], wp[4];
    int oy[4], ox[4], py[4], px[4];
#pragma unroll
    for (int a = 0; a < 4; ++a) {
        wo[a] = wtab[o * 4 + a]; oy[a] = iyb[o * 4 + a]; ox[a] = ixb[o * 4 + a];
        wp[a] = wtab[p * 4 + a]; py[a] = iyb[p * 4 + a]; px[a] = ixb[p * 4 + a];
    }
    float s = 0.0f;
#pragma unroll
    for (int a = 0; a < 4; ++a) {
#pragma unroll
        for (int b = 0; b < 4; ++b) {
            int dy = abs(oy[a] - py[b]);
            int dx = abs(ox[a] - px[b]);
            s += wo[a] * wp[b] * th[dy * RESN + dx];
        }
    }
    bias[idx] = s;
}

// ---------------------------------------------------------------------------
// qkv GEMM (bf16 MFMA): C[m,n] = sum_k X[m,k]*W[n,k]; M=12544, N=1536, K=384
// 64x64 tile, 4 waves; wave wv owns m-rows [m0+16wv, +16).
// ---------------------------------------------------------------------------
__global__ __launch_bounds__(256, 4) void qkv_gemm_mfma(const float* __restrict__ X,
                                                        const float* __restrict__ W,
                                                        float* __restrict__ qb,
                                                        float* __restrict__ kb,
                                                        float* __restrict__ vb) {
    __shared__ short Ak[64][44];   // [m][k], 22-word stride: 2-way frag reads
    __shared__ short Bk[64][44];   // [n][k]

    const int tid = threadIdx.x;
    const int wv = tid >> 6;
    const int lane = tid & 63;
    const int quad = lane >> 4;
    const int l15 = lane & 15;
    const int m0 = blockIdx.x * 64;
    const int n0 = blockIdx.y * 64;

    f32x4v acc[4];
#pragma unroll
    for (int t = 0; t < 4; ++t) { acc[t][0] = 0.f; acc[t][1] = 0.f; acc[t][2] = 0.f; acc[t][3] = 0.f; }

    const int row = tid >> 2, seg = tid & 3;

    for (int k0 = 0; k0 < DIM; k0 += 32) {
        __syncthreads();
        // stage A (x) rows m0..m0+63, cols k0..k0+31
        {
            const float* src = X + (size_t)(m0 + row) * DIM + k0 + seg * 8;
            float4 a = *(const float4*)src;
            float4 c = *(const float4*)(src + 4);
            s16x8 w;
            w[0] = f2bf(a.x); w[1] = f2bf(a.y); w[2] = f2bf(a.z); w[3] = f2bf(a.w);
            w[4] = f2bf(c.x); w[5] = f2bf(c.y); w[6] = f2bf(c.z); w[7] = f2bf(c.w);
            st_frag(&Ak[row][seg * 8], w);
        }
        // stage B (Wqkv) rows n0..n0+63
        {
            const float* src = W + (size_t)(n0 + row) * DIM + k0 + seg * 8;
            float4 a = *(const float4*)src;
            float4 c = *(const float4*)(src + 4);
            s16x8 w;
            w[0] = f2bf(a.x); w[1] = f2bf(a.y); w[2] = f2bf(a.z); w[3] = f2bf(a.w);
            w[4] = f2bf(c.x); w[5] = f2bf(c.y); w[6] = f2bf(c.z); w[7] = f2bf(c.w);
            st_frag(&Bk[row][seg * 8], w);
        }
        __syncthreads();

        s16x8 afr = ld_frag(&Ak[wv * 16 + l15][quad * 8]);
#pragma unroll
        for (int t = 0; t < 4; ++t) {
            s16x8 bfr = ld_frag(&Bk[t * 16 + l15][quad * 8]);
            acc[t] = __builtin_amdgcn_mfma_f32_16x16x32_bf16(afr, bfr, acc[t], 0, 0, 0);
        }
    }

    // epilogue: C-layout (col n = t*16+l15, row m = wv*16+quad*4+r), scatter
#pragma unroll
    for (int t = 0; t < 4; ++t) {
        int n = n0 + t * 16 + l15;
        int head = n / 192;
        int rr = n - head * 192;
#pragma unroll
        for (int r = 0; r < 4; ++r) {
            int m = m0 + wv * 16 + quad * 4 + r;
            int bidx = m / L_SEQ;
            int l = m - bidx * L_SEQ;
            size_t bh = (size_t)bidx * NH + head;
            float val = acc[t][r];
            if (rr < QKD) {
                qb[(bh * L_SEQ + l) * QKD + rr] = val;
            } else if (rr < 2 * QKD) {
                kb[(bh * L_SEQ + l) * QKD + (rr - QKD)] = val;
            } else {
                vb[(bh * L_SEQ + l) * VD + (rr - 2 * QKD)] = val;
            }
        }
    }
}

// ---------------------------------------------------------------------------
// Full-MFMA flash attention (round-4 structure, LDS shapes FIXED: inner dim
// of Vt/Ps must hold the 64-wide k-tile; strides tuned for 2-way bank access).
// Block = (b,h,64-row q-tile), 4 waves; wave w owns q-rows q0+16w..+15.
// Layouts (m89/m120-verified, reconfirmed by r5 bisection): A/B frag:
// m|n=lane&15, k=quad*8+j.  C/D frag: col=lane&15, row=quad*4+reg.
// ---------------------------------------------------------------------------
__global__ __launch_bounds__(256, 4) void flash_attn_mfma2(const float* __restrict__ qg,
                                                           const float* __restrict__ kg,
                                                           const float* __restrict__ vg,
                                                           const float* __restrict__ bias,
                                                           float* __restrict__ o2) {
    __shared__ short Qs[64][44];    // [q-row][d]   (d: 0..31)
    __shared__ short Ks[64][44];    // [k-row][d]
    __shared__ short Vt[VD][68];    // [v-col][k]   (k: 0..63!)
    __shared__ short Ps[64][68];    // [q-row][k]   (k: 0..63!) wave-private rows

    const int tid = threadIdx.x;
    const int wv = tid >> 6;
    const int lane = tid & 63;
    const int quad = lane >> 4;
    const int l15 = lane & 15;

    const int bh = blockIdx.x / NQT;
    const int qt = blockIdx.x - bh * NQT;
    const int b = bh >> 3, h = bh & 7;
    const int q0 = qt * 64;

    const float* qp = qg + (size_t)bh * L_SEQ * QKD;
    const float* kp = kg + (size_t)bh * L_SEQ * QKD;
    const float* vp = vg + (size_t)bh * L_SEQ * VD;
    const float* bbase = bias + (size_t)h * L_SEQ * L_SEQ;

    const float scale = 0.17677669529663687f;  // 32^-0.5, folded into Q

    // ---- stage Q (scaled, bf16) once ----
    {
        int row = tid >> 2, seg = tid & 3;
        int gq = q0 + row; if (gq > L_SEQ - 1) gq = L_SEQ - 1;
        const float* src = qp + (size_t)gq * QKD + seg * 8;
        float4 a = *(const float4*)src;
        float4 c = *(const float4*)(src + 4);
        s16x8 w;
        w[0] = f2bf(a.x * scale); w[1] = f2bf(a.y * scale);
        w[2] = f2bf(a.z * scale); w[3] = f2bf(a.w * scale);
        w[4] = f2bf(c.x * scale); w[5] = f2bf(c.y * scale);
        w[6] = f2bf(c.z * scale); w[7] = f2bf(c.w * scale);
        st_frag(&Qs[row][seg * 8], w);
    }
    __syncthreads();
    s16x8 qfrag = ld_frag(&Qs[wv * 16 + l15][quad * 8]);

    int gqr[4];
#pragma unroll
    for (int r = 0; r < 4; ++r) {
        int g = q0 + wv * 16 + quad * 4 + r;
        gqr[r] = g > L_SEQ - 1 ? L_SEQ - 1 : g;
    }

    f32x4v oacc[8];
#pragma unroll
    for (int vt = 0; vt < 8; ++vt) { oacc[vt][0] = 0.f; oacc[vt][1] = 0.f; oacc[vt][2] = 0.f; oacc[vt][3] = 0.f; }
    float m_i[4] = {-1e30f, -1e30f, -1e30f, -1e30f};
    float l_i[4] = {0.f, 0.f, 0.f, 0.f};

    for (int kt = 0; kt < NKT; ++kt) {
        const int k0 = kt * 64;
        __syncthreads();  // prior tile's readers done
        // ---- stage K (bf16) ----
        {
            int row = tid >> 2, seg = tid & 3;
            int gk = k0 + row; if (gk > L_SEQ - 1) gk = L_SEQ - 1;
            const float* src = kp + (size_t)gk * QKD + seg * 8;
            float4 a = *(const float4*)src;
            float4 c = *(const float4*)(src + 4);
            s16x8 w;
            w[0] = f2bf(a.x); w[1] = f2bf(a.y); w[2] = f2bf(a.z); w[3] = f2bf(a.w);
            w[4] = f2bf(c.x); w[5] = f2bf(c.y); w[6] = f2bf(c.z); w[7] = f2bf(c.w);
            st_frag(&Ks[row][seg * 8], w);
        }
        // ---- stage V transposed: coalesced row reads, b64 column-run writes ----
        {
            int col = tid & 127, rh = tid >> 7;
#pragma unroll
            for (int t = 0; t < 8; ++t) {
                int r0 = (t * 2 + rh) * 4;   // k-runs 0..60
                s16x4 w;
#pragma unroll
                for (int j = 0; j < 4; ++j) {
                    int gr = k0 + r0 + j; if (gr > L_SEQ - 1) gr = L_SEQ - 1;
                    w[j] = f2bf(vp[(size_t)gr * VD + col]);
                }
                *(s16x4*)&Vt[col][r0] = w;
            }
        }
        __syncthreads();

        // ---- QK^T: 4 MFMAs (16 q-rows x 64 k-cols per wave) ----
        f32x4v s[4];
#pragma unroll
        for (int t = 0; t < 4; ++t) {
            s16x8 kf = ld_frag(&Ks[t * 16 + l15][quad * 8]);
            f32x4v z; z[0] = 0.f; z[1] = 0.f; z[2] = 0.f; z[3] = 0.f;
            s[t] = __builtin_amdgcn_mfma_f32_16x16x32_bf16(qfrag, kf, z, 0, 0, 0);
        }
        // ---- + bias (C-layout gather) ----
#pragma unroll
        for (int t = 0; t < 4; ++t) {
            int col = k0 + t * 16 + l15;
            int bc = col > L_SEQ - 1 ? L_SEQ - 1 : col;
#pragma unroll
            for (int r = 0; r < 4; ++r)
                s[t][r] += bbase[(size_t)gqr[r] * L_SEQ + bc];
        }
        // ---- k-tail mask ----
        if (kt == NKT - 1) {
#pragma unroll
            for (int t = 0; t < 4; ++t) {
                if (k0 + t * 16 + l15 >= L_SEQ) {
                    s[t][0] = -1e30f; s[t][1] = -1e30f; s[t][2] = -1e30f; s[t][3] = -1e30f;
                }
            }
        }
        // ---- online softmax (C-layout rows; 16-lane quad groups) ----
        float alpha[4];
#pragma unroll
        for (int r = 0; r < 4; ++r) {
            float mx = fmaxf(fmaxf(s[0][r], s[1][r]), fmaxf(s[2][r], s[3][r]));
            mx = fmaxf(mx, __shfl_xor(mx, 1, 16));
            mx = fmaxf(mx, __shfl_xor(mx, 2, 16));
            mx = fmaxf(mx, __shfl_xor(mx, 4, 16));
            mx = fmaxf(mx, __shfl_xor(mx, 8, 16));
            float mn = fmaxf(m_i[r], mx);
            float ls = 0.f;
#pragma unroll
            for (int t = 0; t < 4; ++t) {
                float p = __expf(s[t][r] - mn);
                s[t][r] = p;
                ls += p;
            }
            ls += __shfl_xor(ls, 1, 16);
            ls += __shfl_xor(ls, 2, 16);
            ls += __shfl_xor(ls, 4, 16);
            ls += __shfl_xor(ls, 8, 16);
            alpha[r] = __expf(m_i[r] - mn);
            m_i[r] = mn;
            l_i[r] = l_i[r] * alpha[r] + ls;
        }
        // ---- P: C-layout -> LDS bf16 -> A-layout (wave-private rows) ----
#pragma unroll
        for (int t = 0; t < 4; ++t)
#pragma unroll
            for (int r = 0; r < 4; ++r)
                Ps[wv * 16 + quad * 4 + r][t * 16 + l15] = f2bf(s[t][r]);
        // ---- rescale O ----
#pragma unroll
        for (int vt = 0; vt < 8; ++vt) {
            oacc[vt][0] *= alpha[0]; oacc[vt][1] *= alpha[1];
            oacc[vt][2] *= alpha[2]; oacc[vt][3] *= alpha[3];
        }
        s16x8 pf0 = ld_frag(&Ps[wv * 16 + l15][quad * 8]);
        s16x8 pf1 = ld_frag(&Ps[wv * 16 + l15][32 + quad * 8]);
        // ---- PV: 16 MFMAs (16 q-rows x 128 v-cols, K=64 in 2 halves) ----
#pragma unroll
        for (int vt = 0; vt < 8; ++vt) {
            int n = vt * 16 + l15;
            s16x8 b0 = ld_frag(&Vt[n][quad * 8]);
            oacc[vt] = __builtin_amdgcn_mfma_f32_16x16x32_bf16(pf0, b0, oacc[vt], 0, 0, 0);
            s16x8 b1 = ld_frag(&Vt[n][32 + quad * 8]);
            oacc[vt] = __builtin_amdgcn_mfma_f32_16x16x32_bf16(pf1, b1, oacc[vt], 0, 0, 0);
        }
    }

    // ---- epilogue: normalize + store (C-layout) ----
    float inv[4];
#pragma unroll
    for (int r = 0; r < 4; ++r) inv[r] = 1.0f / l_i[r];
#pragma unroll
    for (int r = 0; r < 4; ++r) {
        int gq = q0 + wv * 16 + quad * 4 + r;
        if (gq >= L_SEQ) continue;
        float* dst = o2 + ((size_t)b * L_SEQ + gq) * ODIM + h * VD;
#pragma unroll
        for (int vt = 0; vt < 8; ++vt)
            dst[vt * 16 + l15] = oacc[vt][r] * inv[r];
    }
}

// ---------------------------------------------------------------------------
// output projection: out[m,n] = sum_e o2[m,e]*Wproj[n,e] + bproj[n]  (fp32)
// ---------------------------------------------------------------------------
__global__ __launch_bounds__(256) void proj_gemm_kernel(const float* __restrict__ X,
                                                        const float* __restrict__ W,
                                                        const float* __restrict__ bproj,
                                                        float* __restrict__ out) {
    __shared__ float As[16][68];
    __shared__ float Bs[16][68];
    int tid = threadIdx.x;
    int m0 = blockIdx.x * 64;
    int n0 = blockIdx.y * 64;
    int tx = tid & 15, ty = tid >> 4;
    int lr = tid >> 2;
    int lk = (tid & 3) * 4;
    float acc[4][4] = {};
    for (int k0 = 0; k0 < ODIM; k0 += 16) {
        float4 av = *(const float4*)(X + (size_t)(m0 + lr) * ODIM + k0 + lk);
        float4 bv = *(const float4*)(W + (size_t)(n0 + lr) * ODIM + k0 + lk);
        __syncthreads();
        As[lk + 0][lr] = av.x; As[lk + 1][lr] = av.y; As[lk + 2][lr] = av.z; As[lk + 3][lr] = av.w;
        Bs[lk + 0][lr] = bv.x; Bs[lk + 1][lr] = bv.y; Bs[lk + 2][lr] = bv.z; Bs[lk + 3][lr] = bv.w;
        __syncthreads();
#pragma unroll
        for (int kk = 0; kk < 16; ++kk) {
            float4 a = *(const float4*)&As[kk][ty * 4];
            float4 b = *(const float4*)&Bs[kk][tx * 4];
            acc[0][0] += a.x * b.x; acc[0][1] += a.x * b.y; acc[0][2] += a.x * b.z; acc[0][3] += a.x * b.w;
            acc[1][0] += a.y * b.x; acc[1][1] += a.y * b.y; acc[1][2] += a.y * b.z; acc[1][3] += a.y * b.w;
            acc[2][0] += a.z * b.x; acc[2][1] += a.z * b.y; acc[2][2] += a.z * b.z; acc[2][3] += a.z * b.w;
            acc[3][0] += a.w * b.x; acc[3][1] += a.w * b.y; acc[3][2] += a.w * b.z; acc[3][3] += a.w * b.w;
        }
    }
#pragma unroll
    for (int i = 0; i < 4; ++i) {
        int m = m0 + ty * 4 + i;
#pragma unroll
        for (int j = 0; j < 4; ++j) {
            int n = n0 + tx * 4 + j;
            out[(size_t)m * DIM + n] = acc[i][j] + bproj[n];
        }
    }
}

// ---------------------------------------------------------------------------
// launch
// ---------------------------------------------------------------------------
extern "C" void kernel_launch(void* const* d_in, const int* in_sizes, int n_in,
                              void* d_out, int out_size, void* d_ws, size_t ws_size,
                              hipStream_t stream) {
    const float* x      = (const float*)d_in[0];  // (16,784,384)
    const float* Wqkv   = (const float*)d_in[1];  // (1536,384)
    const float* Wproj  = (const float*)d_in[2];  // (384,1024)
    const float* bproj  = (const float*)d_in[3];  // (384,)
    const float* table  = (const float*)d_in[4];  // (8,625)
    float* out = (float*)d_out;

    const size_t QK_SZ = (size_t)B_SZ * NH * L_SEQ * QKD;
    const size_t V_SZ  = (size_t)B_SZ * NH * L_SEQ * VD;
    const size_t BI_SZ = (size_t)NH * L_SEQ * L_SEQ;
    const size_t O2_SZ = (size_t)B_SZ * L_SEQ * ODIM;

    float* ws   = (float*)d_ws;
    float* qb   = ws;
    float* kb   = qb + QK_SZ;
    float* vb   = kb + QK_SZ;
    float* bias = vb + V_SZ;
    float* o2   = bias + BI_SZ;
    float* wtab = o2 + O2_SZ;
    int*   iyb  = (int*)(wtab + L_SEQ * 4);
    int*   ixb  = iyb + L_SEQ * 4;

    interp_tab_kernel<<<(L_SEQ + 255) / 256, 256, 0, stream>>>(wtab, iyb, ixb);

    {
        int total = NH * L_SEQ * L_SEQ;
        bias_kernel<<<(total + 255) / 256, 256, 0, stream>>>(table, wtab, iyb, ixb, bias);
    }

    {
        dim3 grid(12544 / 64, EDIM / 64);  // (196, 24)
        qkv_gemm_mfma<<<grid, 256, 0, stream>>>(x, Wqkv, qb, kb, vb);
    }

    flash_attn_mfma2<<<B_SZ * NH * NQT, 256, 0, stream>>>(qb, kb, vb, bias, o2);

    {
        dim3 grid(12544 / 64, DIM / 64);  // (196, 6)
        proj_gemm_kernel<<<grid, 256, 0, stream>>>(o2, Wproj, bproj, out);
    }
}

// Round 7
// 313.692 us; speedup vs baseline: 8.4081x; 1.5179x over previous
//
#include <hip/hip_runtime.h>
#include <cstddef>

#define L_SEQ 784
#define DIM 384
#define B_SZ 16
#define NH 8
#define QKD 32
#define VD 128
#define EDIM 1536   // NH*(2*QKD+VD)
#define RESN 25
#define NPTS 625    // RESN*RESN
#define ODIM 1024   // NH*VD
#define NQT 13      // ceil(784/64) q-tiles
#define NKT 13      // ceil(784/64) k-tiles

typedef short s16x8 __attribute__((ext_vector_type(8)));
typedef short s16x4 __attribute__((ext_vector_type(4)));
typedef float f32x4v __attribute__((ext_vector_type(4)));

__device__ __forceinline__ short f2bf(float f) {
    union { float f; unsigned u; } c; c.f = f;
    unsigned u = c.u;
    return (short)((u + 0x7FFFu + ((u >> 16) & 1u)) >> 16);
}

// 8-elt bf16 fragment via two b64 ops (rows are 8B-aligned)
__device__ __forceinline__ s16x8 ld_frag(const short* p) {
    s16x4 lo = *(const s16x4*)p;
    s16x4 hi = *(const s16x4*)(p + 4);
    s16x8 r;
    r[0] = lo[0]; r[1] = lo[1]; r[2] = lo[2]; r[3] = lo[3];
    r[4] = hi[0]; r[5] = hi[1]; r[6] = hi[2]; r[7] = hi[3];
    return r;
}

__device__ __forceinline__ void st_frag(short* p, s16x8 w) {
    s16x4 lo, hi;
    lo[0] = w[0]; lo[1] = w[1]; lo[2] = w[2]; lo[3] = w[3];
    hi[0] = w[4]; hi[1] = w[5]; hi[2] = w[6]; hi[3] = w[7];
    *(s16x4*)p = lo;
    *(s16x4*)(p + 4) = hi;
}

// ---------------------------------------------------------------------------
// cubic interpolation weight (a = -0.75)
// ---------------------------------------------------------------------------
__device__ __forceinline__ float cubic_w(float x) {
    float ax = fabsf(x);
    const float a = -0.75f;
    float w1 = ((a + 2.0f) * ax - (a + 3.0f)) * ax * ax + 1.0f;
    float w2 = a * (((ax - 5.0f) * ax + 8.0f) * ax - 4.0f);
    return ax <= 1.0f ? w1 : (ax < 2.0f ? w2 : 0.0f);
}

__global__ void interp_tab_kernel(float* __restrict__ wtab,
                                  int* __restrict__ iyb,
                                  int* __restrict__ ixb) {
    int o = blockIdx.x * blockDim.x + threadIdx.x;
    if (o >= L_SEQ) return;
    const float scale = 625.0f / 784.0f;
    float src = ((float)o + 0.5f) * scale - 0.5f;
    float f = floorf(src);
    float t = src - f;
    int fi = (int)f;
    float w[4];
    w[0] = cubic_w(t + 1.0f);
    w[1] = cubic_w(t);
    w[2] = cubic_w(1.0f - t);
    w[3] = cubic_w(2.0f - t);
#pragma unroll
    for (int j = 0; j < 4; ++j) {
        int idx = fi - 1 + j;
        idx = idx < 0 ? 0 : (idx > NPTS - 1 ? NPTS - 1 : idx);
        wtab[o * 4 + j] = w[j];
        iyb[o * 4 + j] = idx / RESN;
        ixb[o * 4 + j] = idx % RESN;
    }
}

// bias[h][o][p] via 4x4 stencil (interp matrix has 4 nonzeros/row)
__global__ __launch_bounds__(256) void bias_kernel(const float* __restrict__ table,
                                                   const float* __restrict__ wtab,
                                                   const int* __restrict__ iyb,
                                                   const int* __restrict__ ixb,
                                                   float* __restrict__ bias) {
    int idx = blockIdx.x * 256 + threadIdx.x;
    const int total = NH * L_SEQ * L_SEQ;
    if (idx >= total) return;
    int h = idx / (L_SEQ * L_SEQ);
    int rem = idx - h * (L_SEQ * L_SEQ);
    int o = rem / L_SEQ;
    int p = rem - o * L_SEQ;
    const float* th = table + h * NPTS;
    float wo[4], wp[4];
    int oy[4], ox[4], py[4], px[4];
#pragma unroll
    for (int a = 0; a < 4; ++a) {
        wo[a] = wtab[o * 4 + a]; oy[a] = iyb[o * 4 + a]; ox[a] = ixb[o * 4 + a];
        wp[a] = wtab[p * 4 + a]; py[a] = iyb[p * 4 + a]; px[a] = ixb[p * 4 + a];
    }
    float s = 0.0f;
#pragma unroll
    for (int a = 0; a < 4; ++a) {
#pragma unroll
        for (int b = 0; b < 4; ++b) {
            int dy = abs(oy[a] - py[b]);
            int dx = abs(ox[a] - px[b]);
            s += wo[a] * wp[b] * th[dy * RESN + dx];
        }
    }
    bias[idx] = s;
}

// ---------------------------------------------------------------------------
// qkv GEMM (bf16 MFMA): M=12544, N=1536, K=384.
// Outputs bf16: q (pre-scaled) [bh][l][32], k [bh][l][32], vT [bh][d][784].
// ---------------------------------------------------------------------------
__global__ __launch_bounds__(256, 4) void qkv_gemm_mfma(const float* __restrict__ X,
                                                        const float* __restrict__ W,
                                                        short* __restrict__ qb,
                                                        short* __restrict__ kb,
                                                        short* __restrict__ vt) {
    __shared__ short Ak[64][44];
    __shared__ short Bk[64][44];

    const int tid = threadIdx.x;
    const int wv = tid >> 6;
    const int lane = tid & 63;
    const int quad = lane >> 4;
    const int l15 = lane & 15;
    const int m0 = blockIdx.x * 64;
    const int n0 = blockIdx.y * 64;

    f32x4v acc[4];
#pragma unroll
    for (int t = 0; t < 4; ++t) { acc[t][0] = 0.f; acc[t][1] = 0.f; acc[t][2] = 0.f; acc[t][3] = 0.f; }

    const int row = tid >> 2, seg = tid & 3;

    for (int k0 = 0; k0 < DIM; k0 += 32) {
        __syncthreads();
        {
            const float* src = X + (size_t)(m0 + row) * DIM + k0 + seg * 8;
            float4 a = *(const float4*)src;
            float4 c = *(const float4*)(src + 4);
            s16x8 w;
            w[0] = f2bf(a.x); w[1] = f2bf(a.y); w[2] = f2bf(a.z); w[3] = f2bf(a.w);
            w[4] = f2bf(c.x); w[5] = f2bf(c.y); w[6] = f2bf(c.z); w[7] = f2bf(c.w);
            st_frag(&Ak[row][seg * 8], w);
        }
        {
            const float* src = W + (size_t)(n0 + row) * DIM + k0 + seg * 8;
            float4 a = *(const float4*)src;
            float4 c = *(const float4*)(src + 4);
            s16x8 w;
            w[0] = f2bf(a.x); w[1] = f2bf(a.y); w[2] = f2bf(a.z); w[3] = f2bf(a.w);
            w[4] = f2bf(c.x); w[5] = f2bf(c.y); w[6] = f2bf(c.z); w[7] = f2bf(c.w);
            st_frag(&Bk[row][seg * 8], w);
        }
        __syncthreads();

        s16x8 afr = ld_frag(&Ak[wv * 16 + l15][quad * 8]);
#pragma unroll
        for (int t = 0; t < 4; ++t) {
            s16x8 bfr = ld_frag(&Bk[t * 16 + l15][quad * 8]);
            acc[t] = __builtin_amdgcn_mfma_f32_16x16x32_bf16(afr, bfr, acc[t], 0, 0, 0);
        }
    }

    const float SCALE = 0.17677669529663687f;  // 32^-0.5, folded into q

    // epilogue: C-layout (col n = t*16+l15, row m = wv*16+quad*4+r)
#pragma unroll
    for (int t = 0; t < 4; ++t) {
        int n = n0 + t * 16 + l15;
        int head = n / 192;
        int rr = n - head * 192;
        int mbase = m0 + wv * 16 + quad * 4;
        int bidx = mbase / L_SEQ;             // 4-run never crosses (784 % 4 == 0)
        int l0 = mbase - bidx * L_SEQ;
        size_t bh = (size_t)bidx * NH + head;
        if (rr < QKD) {
#pragma unroll
            for (int r = 0; r < 4; ++r)
                qb[(bh * L_SEQ + l0 + r) * QKD + rr] = f2bf(acc[t][r] * SCALE);
        } else if (rr < 2 * QKD) {
#pragma unroll
            for (int r = 0; r < 4; ++r)
                kb[(bh * L_SEQ + l0 + r) * QKD + (rr - QKD)] = f2bf(acc[t][r]);
        } else {
            s16x4 pk;
#pragma unroll
            for (int r = 0; r < 4; ++r) pk[r] = f2bf(acc[t][r]);
            *(s16x4*)&vt[((size_t)bh * VD + (rr - 2 * QKD)) * L_SEQ + l0] = pk;
        }
    }
}

// ---------------------------------------------------------------------------
// Full-MFMA flash attention. Inputs already bf16 (q pre-scaled, V transposed).
// XCD swizzle: h = blockIdx&7 so each XCD's L2 holds one head's bias.
// A/B frag: m|n=lane&15, k=quad*8+j.  C/D frag: col=lane&15, row=quad*4+reg.
// ---------------------------------------------------------------------------
__global__ __launch_bounds__(256, 4) void flash_attn_mfma3(const short* __restrict__ qg,
                                                           const short* __restrict__ kg,
                                                           const short* __restrict__ vtg,
                                                           const float* __restrict__ bias,
                                                           short* __restrict__ o2) {
    __shared__ short Qs[64][44];    // [q-row][d]
    __shared__ short Ks[64][44];    // [k-row][d]
    __shared__ short Vt[VD][68];    // [v-col][k 0..63]
    __shared__ short Ps[64][68];    // [q-row][k 0..63] wave-private rows

    const int tid = threadIdx.x;
    const int wv = tid >> 6;
    const int lane = tid & 63;
    const int quad = lane >> 4;
    const int l15 = lane & 15;

    // XCD-aware decomposition: 1664 blocks = 208 slots x 8 heads
    const int h = blockIdx.x & 7;
    const int slot = blockIdx.x >> 3;
    const int b = slot / NQT;
    const int qt = slot - b * NQT;
    const int bh = b * NH + h;
    const int q0 = qt * 64;

    const short* qp = qg + (size_t)bh * L_SEQ * QKD;
    const short* kp = kg + (size_t)bh * L_SEQ * QKD;
    const short* vp = vtg + (size_t)bh * VD * L_SEQ;
    const float* bbase = bias + (size_t)h * L_SEQ * L_SEQ;

    // ---- stage Q once (pure copy) ----
    {
        int row = tid >> 2, seg = tid & 3;
        int gq = q0 + row; if (gq > L_SEQ - 1) gq = L_SEQ - 1;
        s16x8 w = *(const s16x8*)(qp + (size_t)gq * QKD + seg * 8);
        st_frag(&Qs[row][seg * 8], w);
    }
    __syncthreads();
    s16x8 qfrag = ld_frag(&Qs[wv * 16 + l15][quad * 8]);

    int gqr[4];
#pragma unroll
    for (int r = 0; r < 4; ++r) {
        int g = q0 + wv * 16 + quad * 4 + r;
        gqr[r] = g > L_SEQ - 1 ? L_SEQ - 1 : g;
    }

    f32x4v oacc[8];
#pragma unroll
    for (int vt = 0; vt < 8; ++vt) { oacc[vt][0] = 0.f; oacc[vt][1] = 0.f; oacc[vt][2] = 0.f; oacc[vt][3] = 0.f; }
    float m_i[4] = {-1e30f, -1e30f, -1e30f, -1e30f};
    float l_i[4] = {0.f, 0.f, 0.f, 0.f};

    for (int kt = 0; kt < NKT; ++kt) {
        const int k0 = kt * 64;
        __syncthreads();
        // ---- stage K (pure copy) ----
        {
            int row = tid >> 2, seg = tid & 3;
            int gk = k0 + row; if (gk > L_SEQ - 1) gk = L_SEQ - 1;
            s16x8 w = *(const s16x8*)(kp + (size_t)gk * QKD + seg * 8);
            st_frag(&Ks[row][seg * 8], w);
        }
        // ---- stage V tile (pure copy from pre-transposed vT) ----
        {
            int d = tid >> 1;
            int c0 = (tid & 1) * 32;
            const short* src = vp + (size_t)d * L_SEQ;
#pragma unroll
            for (int j = 0; j < 4; ++j) {
                int cb = k0 + c0 + j * 8;
                if (cb > L_SEQ - 8) cb = L_SEQ - 8;   // clamp: finite vals, masked below
                s16x8 w = *(const s16x8*)(src + cb);
                st_frag(&Vt[d][c0 + j * 8], w);
            }
        }
        __syncthreads();

        // ---- QK^T: 4 MFMAs ----
        f32x4v s[4];
#pragma unroll
        for (int t = 0; t < 4; ++t) {
            s16x8 kf = ld_frag(&Ks[t * 16 + l15][quad * 8]);
            f32x4v z; z[0] = 0.f; z[1] = 0.f; z[2] = 0.f; z[3] = 0.f;
            s[t] = __builtin_amdgcn_mfma_f32_16x16x32_bf16(qfrag, kf, z, 0, 0, 0);
        }
        // ---- + bias (C-layout gather; L2-resident after swizzle) ----
#pragma unroll
        for (int t = 0; t < 4; ++t) {
            int col = k0 + t * 16 + l15;
            int bc = col > L_SEQ - 1 ? L_SEQ - 1 : col;
#pragma unroll
            for (int r = 0; r < 4; ++r)
                s[t][r] += bbase[(size_t)gqr[r] * L_SEQ + bc];
        }
        // ---- k-tail mask ----
        if (kt == NKT - 1) {
#pragma unroll
            for (int t = 0; t < 4; ++t) {
                if (k0 + t * 16 + l15 >= L_SEQ) {
                    s[t][0] = -1e30f; s[t][1] = -1e30f; s[t][2] = -1e30f; s[t][3] = -1e30f;
                }
            }
        }
        // ---- online softmax ----
        float alpha[4];
#pragma unroll
        for (int r = 0; r < 4; ++r) {
            float mx = fmaxf(fmaxf(s[0][r], s[1][r]), fmaxf(s[2][r], s[3][r]));
            mx = fmaxf(mx, __shfl_xor(mx, 1, 16));
            mx = fmaxf(mx, __shfl_xor(mx, 2, 16));
            mx = fmaxf(mx, __shfl_xor(mx, 4, 16));
            mx = fmaxf(mx, __shfl_xor(mx, 8, 16));
            float mn = fmaxf(m_i[r], mx);
            float ls = 0.f;
#pragma unroll
            for (int t = 0; t < 4; ++t) {
                float p = __expf(s[t][r] - mn);
                s[t][r] = p;
                ls += p;
            }
            ls += __shfl_xor(ls, 1, 16);
            ls += __shfl_xor(ls, 2, 16);
            ls += __shfl_xor(ls, 4, 16);
            ls += __shfl_xor(ls, 8, 16);
            alpha[r] = __expf(m_i[r] - mn);
            m_i[r] = mn;
            l_i[r] = l_i[r] * alpha[r] + ls;
        }
        // ---- P -> LDS bf16 (wave-private rows) ----
#pragma unroll
        for (int t = 0; t < 4; ++t)
#pragma unroll
            for (int r = 0; r < 4; ++r)
                Ps[wv * 16 + quad * 4 + r][t * 16 + l15] = f2bf(s[t][r]);
        // ---- rescale O ----
#pragma unroll
        for (int vt = 0; vt < 8; ++vt) {
            oacc[vt][0] *= alpha[0]; oacc[vt][1] *= alpha[1];
            oacc[vt][2] *= alpha[2]; oacc[vt][3] *= alpha[3];
        }
        s16x8 pf0 = ld_frag(&Ps[wv * 16 + l15][quad * 8]);
        s16x8 pf1 = ld_frag(&Ps[wv * 16 + l15][32 + quad * 8]);
        // ---- PV: 16 MFMAs ----
#pragma unroll
        for (int vt = 0; vt < 8; ++vt) {
            int n = vt * 16 + l15;
            s16x8 b0 = ld_frag(&Vt[n][quad * 8]);
            oacc[vt] = __builtin_amdgcn_mfma_f32_16x16x32_bf16(pf0, b0, oacc[vt], 0, 0, 0);
            s16x8 b1 = ld_frag(&Vt[n][32 + quad * 8]);
            oacc[vt] = __builtin_amdgcn_mfma_f32_16x16x32_bf16(pf1, b1, oacc[vt], 0, 0, 0);
        }
    }

    // ---- epilogue: normalize + store bf16 (C-layout) ----
    float inv[4];
#pragma unroll
    for (int r = 0; r < 4; ++r) inv[r] = 1.0f / l_i[r];
#pragma unroll
    for (int r = 0; r < 4; ++r) {
        int gq = q0 + wv * 16 + quad * 4 + r;
        if (gq >= L_SEQ) continue;
        short* dst = o2 + ((size_t)b * L_SEQ + gq) * ODIM + h * VD;
#pragma unroll
        for (int vt = 0; vt < 8; ++vt)
            dst[vt * 16 + l15] = f2bf(oacc[vt][r] * inv[r]);
    }
}

// ---------------------------------------------------------------------------
// proj GEMM (bf16 MFMA): out[m,n] = sum_e o2[m,e]*Wproj[n,e] + bproj[n]
// M=12544, N=384, K=1024; A already bf16 (o2), B converted in staging.
// ---------------------------------------------------------------------------
__global__ __launch_bounds__(256, 4) void proj_gemm_mfma(const short* __restrict__ X,
                                                         const float* __restrict__ W,
                                                         const float* __restrict__ bproj,
                                                         float* __restrict__ out) {
    __shared__ short Ak[64][44];
    __shared__ short Bk[64][44];

    const int tid = threadIdx.x;
    const int wv = tid >> 6;
    const int lane = tid & 63;
    const int quad = lane >> 4;
    const int l15 = lane & 15;
    const int m0 = blockIdx.x * 64;
    const int n0 = blockIdx.y * 64;

    f32x4v acc[4];
#pragma unroll
    for (int t = 0; t < 4; ++t) { acc[t][0] = 0.f; acc[t][1] = 0.f; acc[t][2] = 0.f; acc[t][3] = 0.f; }

    const int row = tid >> 2, seg = tid & 3;

    for (int k0 = 0; k0 < ODIM; k0 += 32) {
        __syncthreads();
        {
            s16x8 w = *(const s16x8*)(X + (size_t)(m0 + row) * ODIM + k0 + seg * 8);
            st_frag(&Ak[row][seg * 8], w);
        }
        {
            const float* src = W + (size_t)(n0 + row) * ODIM + k0 + seg * 8;
            float4 a = *(const float4*)src;
            float4 c = *(const float4*)(src + 4);
            s16x8 w;
            w[0] = f2bf(a.x); w[1] = f2bf(a.y); w[2] = f2bf(a.z); w[3] = f2bf(a.w);
            w[4] = f2bf(c.x); w[5] = f2bf(c.y); w[6] = f2bf(c.z); w[7] = f2bf(c.w);
            st_frag(&Bk[row][seg * 8], w);
        }
        __syncthreads();

        s16x8 afr = ld_frag(&Ak[wv * 16 + l15][quad * 8]);
#pragma unroll
        for (int t = 0; t < 4; ++t) {
            s16x8 bfr = ld_frag(&Bk[t * 16 + l15][quad * 8]);
            acc[t] = __builtin_amdgcn_mfma_f32_16x16x32_bf16(afr, bfr, acc[t], 0, 0, 0);
        }
    }

#pragma unroll
    for (int t = 0; t < 4; ++t) {
        int n = n0 + t * 16 + l15;
        float bp = bproj[n];
#pragma unroll
        for (int r = 0; r < 4; ++r) {
            int m = m0 + wv * 16 + quad * 4 + r;
            out[(size_t)m * DIM + n] = acc[t][r] + bp;
        }
    }
}

// ---------------------------------------------------------------------------
// launch
// ---------------------------------------------------------------------------
extern "C" void kernel_launch(void* const* d_in, const int* in_sizes, int n_in,
                              void* d_out, int out_size, void* d_ws, size_t ws_size,
                              hipStream_t stream) {
    const float* x      = (const float*)d_in[0];  // (16,784,384)
    const float* Wqkv   = (const float*)d_in[1];  // (1536,384)
    const float* Wproj  = (const float*)d_in[2];  // (384,1024)
    const float* bproj  = (const float*)d_in[3];  // (384,)
    const float* table  = (const float*)d_in[4];  // (8,625)
    float* out = (float*)d_out;

    const size_t QK_SZ = (size_t)B_SZ * NH * L_SEQ * QKD;   // shorts
    const size_t V_SZ  = (size_t)B_SZ * NH * L_SEQ * VD;    // shorts
    const size_t BI_SZ = (size_t)NH * L_SEQ * L_SEQ;        // floats
    const size_t O2_SZ = (size_t)B_SZ * L_SEQ * ODIM;       // shorts

    short* qb   = (short*)d_ws;
    short* kb   = qb + QK_SZ;
    short* vt   = kb + QK_SZ;
    float* bias = (float*)(vt + V_SZ);
    short* o2   = (short*)(bias + BI_SZ);
    float* wtab = (float*)(o2 + O2_SZ);
    int*   iyb  = (int*)(wtab + L_SEQ * 4);
    int*   ixb  = iyb + L_SEQ * 4;

    interp_tab_kernel<<<(L_SEQ + 255) / 256, 256, 0, stream>>>(wtab, iyb, ixb);

    {
        int total = NH * L_SEQ * L_SEQ;
        bias_kernel<<<(total + 255) / 256, 256, 0, stream>>>(table, wtab, iyb, ixb, bias);
    }

    {
        dim3 grid(12544 / 64, EDIM / 64);  // (196, 24)
        qkv_gemm_mfma<<<grid, 256, 0, stream>>>(x, Wqkv, qb, kb, vt);
    }

    flash_attn_mfma3<<<B_SZ * NH * NQT, 256, 0, stream>>>(qb, kb, vt, bias, o2);

    {
        dim3 grid(12544 / 64, DIM / 64);  // (196, 6)
        proj_gemm_mfma<<<grid, 256, 0, stream>>>(o2, Wproj, bproj, out);
    }
}

// Round 8
// 303.607 us; speedup vs baseline: 8.6874x; 1.0332x over previous
//
#include <hip/hip_runtime.h>
#include <cstddef>

#define L_SEQ 784
#define DIM 384
#define B_SZ 16
#define NH 8
#define QKD 32
#define VD 128
#define EDIM 1536   // NH*(2*QKD+VD)
#define RESN 25
#define NPTS 625    // RESN*RESN
#define ODIM 1024   // NH*VD
#define NQT 13      // ceil(784/64) q-tiles
#define NKT 13      // ceil(784/64) k-tiles

typedef short s16x8 __attribute__((ext_vector_type(8)));
typedef short s16x4 __attribute__((ext_vector_type(4)));
typedef float f32x4v __attribute__((ext_vector_type(4)));

__device__ __forceinline__ short f2bf(float f) {
    union { float f; unsigned u; } c; c.f = f;
    unsigned u = c.u;
    return (short)((u + 0x7FFFu + ((u >> 16) & 1u)) >> 16);
}

// 8-elt bf16 fragment via two b64 ops (for 8B-aligned rows: attn kernel)
__device__ __forceinline__ s16x8 ld_frag(const short* p) {
    s16x4 lo = *(const s16x4*)p;
    s16x4 hi = *(const s16x4*)(p + 4);
    s16x8 r;
    r[0] = lo[0]; r[1] = lo[1]; r[2] = lo[2]; r[3] = lo[3];
    r[4] = hi[0]; r[5] = hi[1]; r[6] = hi[2]; r[7] = hi[3];
    return r;
}

__device__ __forceinline__ void st_frag(short* p, s16x8 w) {
    s16x4 lo, hi;
    lo[0] = w[0]; lo[1] = w[1]; lo[2] = w[2]; lo[3] = w[3];
    hi[0] = w[4]; hi[1] = w[5]; hi[2] = w[6]; hi[3] = w[7];
    *(s16x4*)p = lo;
    *(s16x4*)(p + 4) = hi;
}

// ---------------------------------------------------------------------------
// fp32 -> bf16 bulk convert (8 elts/thread)
// ---------------------------------------------------------------------------
__global__ __launch_bounds__(256) void cvt_bf16_kernel(const float* __restrict__ src,
                                                       short* __restrict__ dst, int n8) {
    int i = blockIdx.x * 256 + threadIdx.x;
    if (i >= n8) return;
    const float4* s = (const float4*)(src + (size_t)i * 8);
    float4 a = s[0], c = s[1];
    s16x8 w;
    w[0] = f2bf(a.x); w[1] = f2bf(a.y); w[2] = f2bf(a.z); w[3] = f2bf(a.w);
    w[4] = f2bf(c.x); w[5] = f2bf(c.y); w[6] = f2bf(c.z); w[7] = f2bf(c.w);
    *(s16x8*)(dst + (size_t)i * 8) = w;
}

// ---------------------------------------------------------------------------
// cubic interpolation weight (a = -0.75)
// ---------------------------------------------------------------------------
__device__ __forceinline__ float cubic_w(float x) {
    float ax = fabsf(x);
    const float a = -0.75f;
    float w1 = ((a + 2.0f) * ax - (a + 3.0f)) * ax * ax + 1.0f;
    float w2 = a * (((ax - 5.0f) * ax + 8.0f) * ax - 4.0f);
    return ax <= 1.0f ? w1 : (ax < 2.0f ? w2 : 0.0f);
}

__global__ void interp_tab_kernel(float* __restrict__ wtab,
                                  int* __restrict__ iyb,
                                  int* __restrict__ ixb) {
    int o = blockIdx.x * blockDim.x + threadIdx.x;
    if (o >= L_SEQ) return;
    const float scale = 625.0f / 784.0f;
    float src = ((float)o + 0.5f) * scale - 0.5f;
    float f = floorf(src);
    float t = src - f;
    int fi = (int)f;
    float w[4];
    w[0] = cubic_w(t + 1.0f);
    w[1] = cubic_w(t);
    w[2] = cubic_w(1.0f - t);
    w[3] = cubic_w(2.0f - t);
#pragma unroll
    for (int j = 0; j < 4; ++j) {
        int idx = fi - 1 + j;
        idx = idx < 0 ? 0 : (idx > NPTS - 1 ? NPTS - 1 : idx);
        wtab[o * 4 + j] = w[j];
        iyb[o * 4 + j] = idx / RESN;
        ixb[o * 4 + j] = idx % RESN;
    }
}

// bias[h][o][p] via 4x4 stencil (interp matrix has 4 nonzeros/row)
__global__ __launch_bounds__(256) void bias_kernel(const float* __restrict__ table,
                                                   const float* __restrict__ wtab,
                                                   const int* __restrict__ iyb,
                                                   const int* __restrict__ ixb,
                                                   float* __restrict__ bias) {
    int idx = blockIdx.x * 256 + threadIdx.x;
    const int total = NH * L_SEQ * L_SEQ;
    if (idx >= total) return;
    int h = idx / (L_SEQ * L_SEQ);
    int rem = idx - h * (L_SEQ * L_SEQ);
    int o = rem / L_SEQ;
    int p = rem - o * L_SEQ;
    const float* th = table + h * NPTS;
    float wo[4], wp[4];
    int oy[4], ox[4], py[4], px[4];
#pragma unroll
    for (int a = 0; a < 4; ++a) {
        wo[a] = wtab[o * 4 + a]; oy[a] = iyb[o * 4 + a]; ox[a] = ixb[o * 4 + a];
        wp[a] = wtab[p * 4 + a]; py[a] = iyb[p * 4 + a]; px[a] = ixb[p * 4 + a];
    }
    float s = 0.0f;
#pragma unroll
    for (int a = 0; a < 4; ++a) {
#pragma unroll
        for (int b = 0; b < 4; ++b) {
            int dy = abs(oy[a] - py[b]);
            int dx = abs(ox[a] - px[b]);
            s += wo[a] * wp[b] * th[dy * RESN + dx];
        }
    }
    bias[idx] = s;
}

// ---------------------------------------------------------------------------
// qkv GEMM (bf16 in, 128x128 tile, 4 waves in 2x2 quadrants, BK=32).
// LDS rows padded to 48 shorts (96 B) -> all fragment reads are aligned b128.
// Outputs bf16: q (pre-scaled) [bh][l][32], k [bh][l][32], vT [bh][d][784].
// ---------------------------------------------------------------------------
__global__ __launch_bounds__(256) void qkv_gemm_mfma(const short* __restrict__ Xb,
                                                     const short* __restrict__ Wb,
                                                     short* __restrict__ qb,
                                                     short* __restrict__ kb,
                                                     short* __restrict__ vt) {
    __shared__ short Ak[128][48];
    __shared__ short Bk[128][48];

    const int tid = threadIdx.x;
    const int wv = tid >> 6;
    const int lane = tid & 63;
    const int quad = lane >> 4;
    const int l15 = lane & 15;
    const int wr = wv >> 1, wc = wv & 1;
    const int m0 = blockIdx.x * 128;
    const int n0 = blockIdx.y * 128;

    f32x4v acc[4][4];
#pragma unroll
    for (int i = 0; i < 4; ++i)
#pragma unroll
        for (int j = 0; j < 4; ++j) { acc[i][j][0] = 0.f; acc[i][j][1] = 0.f; acc[i][j][2] = 0.f; acc[i][j][3] = 0.f; }

    for (int k0 = 0; k0 < DIM; k0 += 32) {
        __syncthreads();
#pragma unroll
        for (int it = 0; it < 2; ++it) {
            int idx = it * 256 + tid;
            int row = idx >> 2, seg = idx & 3;
            *(s16x8*)&Ak[row][seg * 8] = *(const s16x8*)(Xb + (size_t)(m0 + row) * DIM + k0 + seg * 8);
            *(s16x8*)&Bk[row][seg * 8] = *(const s16x8*)(Wb + (size_t)(n0 + row) * DIM + k0 + seg * 8);
        }
        __syncthreads();

        s16x8 af[4], bfr[4];
#pragma unroll
        for (int i = 0; i < 4; ++i) af[i] = *(const s16x8*)&Ak[wr * 64 + i * 16 + l15][quad * 8];
#pragma unroll
        for (int j = 0; j < 4; ++j) bfr[j] = *(const s16x8*)&Bk[wc * 64 + j * 16 + l15][quad * 8];
#pragma unroll
        for (int i = 0; i < 4; ++i)
#pragma unroll
            for (int j = 0; j < 4; ++j)
                acc[i][j] = __builtin_amdgcn_mfma_f32_16x16x32_bf16(af[i], bfr[j], acc[i][j], 0, 0, 0);
    }

    const float SCALE = 0.17677669529663687f;  // 32^-0.5, folded into q

    // epilogue: C-layout (col n, row m = quad*4+r), scatter to q/k/vT
#pragma unroll
    for (int j = 0; j < 4; ++j) {
        int n = n0 + wc * 64 + j * 16 + l15;
        int head = n / 192;
        int rr = n - head * 192;
#pragma unroll
        for (int i = 0; i < 4; ++i) {
            int mbase = m0 + wr * 64 + i * 16 + quad * 4;
            int bidx = mbase / L_SEQ;           // 4-run never crosses (784 % 4 == 0)
            int l0 = mbase - bidx * L_SEQ;
            size_t bh = (size_t)bidx * NH + head;
            if (rr < QKD) {
#pragma unroll
                for (int r = 0; r < 4; ++r)
                    qb[(bh * L_SEQ + l0 + r) * QKD + rr] = f2bf(acc[i][j][r] * SCALE);
            } else if (rr < 2 * QKD) {
#pragma unroll
                for (int r = 0; r < 4; ++r)
                    kb[(bh * L_SEQ + l0 + r) * QKD + (rr - QKD)] = f2bf(acc[i][j][r]);
            } else {
                s16x4 pk;
#pragma unroll
                for (int r = 0; r < 4; ++r) pk[r] = f2bf(acc[i][j][r]);
                *(s16x4*)&vt[((size_t)bh * VD + (rr - 2 * QKD)) * L_SEQ + l0] = pk;
            }
        }
    }
}

// ---------------------------------------------------------------------------
// Full-MFMA flash attention (round-7, unchanged). Inputs bf16, V transposed.
// XCD swizzle: h = blockIdx&7 so each XCD's L2 holds one head's bias.
// ---------------------------------------------------------------------------
__global__ __launch_bounds__(256, 4) void flash_attn_mfma3(const short* __restrict__ qg,
                                                           const short* __restrict__ kg,
                                                           const short* __restrict__ vtg,
                                                           const float* __restrict__ bias,
                                                           short* __restrict__ o2) {
    __shared__ short Qs[64][44];    // [q-row][d]
    __shared__ short Ks[64][44];    // [k-row][d]
    __shared__ short Vt[VD][68];    // [v-col][k 0..63]
    __shared__ short Ps[64][68];    // [q-row][k 0..63] wave-private rows

    const int tid = threadIdx.x;
    const int wv = tid >> 6;
    const int lane = tid & 63;
    const int quad = lane >> 4;
    const int l15 = lane & 15;

    const int h = blockIdx.x & 7;
    const int slot = blockIdx.x >> 3;
    const int b = slot / NQT;
    const int qt = slot - b * NQT;
    const int bh = b * NH + h;
    const int q0 = qt * 64;

    const short* qp = qg + (size_t)bh * L_SEQ * QKD;
    const short* kp = kg + (size_t)bh * L_SEQ * QKD;
    const short* vp = vtg + (size_t)bh * VD * L_SEQ;
    const float* bbase = bias + (size_t)h * L_SEQ * L_SEQ;

    {
        int row = tid >> 2, seg = tid & 3;
        int gq = q0 + row; if (gq > L_SEQ - 1) gq = L_SEQ - 1;
        s16x8 w = *(const s16x8*)(qp + (size_t)gq * QKD + seg * 8);
        st_frag(&Qs[row][seg * 8], w);
    }
    __syncthreads();
    s16x8 qfrag = ld_frag(&Qs[wv * 16 + l15][quad * 8]);

    int gqr[4];
#pragma unroll
    for (int r = 0; r < 4; ++r) {
        int g = q0 + wv * 16 + quad * 4 + r;
        gqr[r] = g > L_SEQ - 1 ? L_SEQ - 1 : g;
    }

    f32x4v oacc[8];
#pragma unroll
    for (int vt = 0; vt < 8; ++vt) { oacc[vt][0] = 0.f; oacc[vt][1] = 0.f; oacc[vt][2] = 0.f; oacc[vt][3] = 0.f; }
    float m_i[4] = {-1e30f, -1e30f, -1e30f, -1e30f};
    float l_i[4] = {0.f, 0.f, 0.f, 0.f};

    for (int kt = 0; kt < NKT; ++kt) {
        const int k0 = kt * 64;
        __syncthreads();
        {
            int row = tid >> 2, seg = tid & 3;
            int gk = k0 + row; if (gk > L_SEQ - 1) gk = L_SEQ - 1;
            s16x8 w = *(const s16x8*)(kp + (size_t)gk * QKD + seg * 8);
            st_frag(&Ks[row][seg * 8], w);
        }
        {
            int d = tid >> 1;
            int c0 = (tid & 1) * 32;
            const short* src = vp + (size_t)d * L_SEQ;
#pragma unroll
            for (int j = 0; j < 4; ++j) {
                int cb = k0 + c0 + j * 8;
                if (cb > L_SEQ - 8) cb = L_SEQ - 8;
                s16x8 w = *(const s16x8*)(src + cb);
                st_frag(&Vt[d][c0 + j * 8], w);
            }
        }
        __syncthreads();

        f32x4v s[4];
#pragma unroll
        for (int t = 0; t < 4; ++t) {
            s16x8 kf = ld_frag(&Ks[t * 16 + l15][quad * 8]);
            f32x4v z; z[0] = 0.f; z[1] = 0.f; z[2] = 0.f; z[3] = 0.f;
            s[t] = __builtin_amdgcn_mfma_f32_16x16x32_bf16(qfrag, kf, z, 0, 0, 0);
        }
#pragma unroll
        for (int t = 0; t < 4; ++t) {
            int col = k0 + t * 16 + l15;
            int bc = col > L_SEQ - 1 ? L_SEQ - 1 : col;
#pragma unroll
            for (int r = 0; r < 4; ++r)
                s[t][r] += bbase[(size_t)gqr[r] * L_SEQ + bc];
        }
        if (kt == NKT - 1) {
#pragma unroll
            for (int t = 0; t < 4; ++t) {
                if (k0 + t * 16 + l15 >= L_SEQ) {
                    s[t][0] = -1e30f; s[t][1] = -1e30f; s[t][2] = -1e30f; s[t][3] = -1e30f;
                }
            }
        }
        float alpha[4];
#pragma unroll
        for (int r = 0; r < 4; ++r) {
            float mx = fmaxf(fmaxf(s[0][r], s[1][r]), fmaxf(s[2][r], s[3][r]));
            mx = fmaxf(mx, __shfl_xor(mx, 1, 16));
            mx = fmaxf(mx, __shfl_xor(mx, 2, 16));
            mx = fmaxf(mx, __shfl_xor(mx, 4, 16));
            mx = fmaxf(mx, __shfl_xor(mx, 8, 16));
            float mn = fmaxf(m_i[r], mx);
            float ls = 0.f;
#pragma unroll
            for (int t = 0; t < 4; ++t) {
                float p = __expf(s[t][r] - mn);
                s[t][r] = p;
                ls += p;
            }
            ls += __shfl_xor(ls, 1, 16);
            ls += __shfl_xor(ls, 2, 16);
            ls += __shfl_xor(ls, 4, 16);
            ls += __shfl_xor(ls, 8, 16);
            alpha[r] = __expf(m_i[r] - mn);
            m_i[r] = mn;
            l_i[r] = l_i[r] * alpha[r] + ls;
        }
#pragma unroll
        for (int t = 0; t < 4; ++t)
#pragma unroll
            for (int r = 0; r < 4; ++r)
                Ps[wv * 16 + quad * 4 + r][t * 16 + l15] = f2bf(s[t][r]);
#pragma unroll
        for (int vt = 0; vt < 8; ++vt) {
            oacc[vt][0] *= alpha[0]; oacc[vt][1] *= alpha[1];
            oacc[vt][2] *= alpha[2]; oacc[vt][3] *= alpha[3];
        }
        s16x8 pf0 = ld_frag(&Ps[wv * 16 + l15][quad * 8]);
        s16x8 pf1 = ld_frag(&Ps[wv * 16 + l15][32 + quad * 8]);
#pragma unroll
        for (int vt = 0; vt < 8; ++vt) {
            int n = vt * 16 + l15;
            s16x8 b0 = ld_frag(&Vt[n][quad * 8]);
            oacc[vt] = __builtin_amdgcn_mfma_f32_16x16x32_bf16(pf0, b0, oacc[vt], 0, 0, 0);
            s16x8 b1 = ld_frag(&Vt[n][32 + quad * 8]);
            oacc[vt] = __builtin_amdgcn_mfma_f32_16x16x32_bf16(pf1, b1, oacc[vt], 0, 0, 0);
        }
    }

    float inv[4];
#pragma unroll
    for (int r = 0; r < 4; ++r) inv[r] = 1.0f / l_i[r];
#pragma unroll
    for (int r = 0; r < 4; ++r) {
        int gq = q0 + wv * 16 + quad * 4 + r;
        if (gq >= L_SEQ) continue;
        short* dst = o2 + ((size_t)b * L_SEQ + gq) * ODIM + h * VD;
#pragma unroll
        for (int vt = 0; vt < 8; ++vt)
            dst[vt * 16 + l15] = f2bf(oacc[vt][r] * inv[r]);
    }
}

// ---------------------------------------------------------------------------
// proj GEMM (bf16 in, 128x128 tile, BK=32): out = o2 @ WprojT + bproj (fp32)
// M=12544, N=384, K=1024
// ---------------------------------------------------------------------------
__global__ __launch_bounds__(256) void proj_gemm_mfma(const short* __restrict__ Xb,
                                                      const short* __restrict__ Wb,
                                                      const float* __restrict__ bproj,
                                                      float* __restrict__ out) {
    __shared__ short Ak[128][48];
    __shared__ short Bk[128][48];

    const int tid = threadIdx.x;
    const int wv = tid >> 6;
    const int lane = tid & 63;
    const int quad = lane >> 4;
    const int l15 = lane & 15;
    const int wr = wv >> 1, wc = wv & 1;
    const int m0 = blockIdx.x * 128;
    const int n0 = blockIdx.y * 128;

    f32x4v acc[4][4];
#pragma unroll
    for (int i = 0; i < 4; ++i)
#pragma unroll
        for (int j = 0; j < 4; ++j) { acc[i][j][0] = 0.f; acc[i][j][1] = 0.f; acc[i][j][2] = 0.f; acc[i][j][3] = 0.f; }

    for (int k0 = 0; k0 < ODIM; k0 += 32) {
        __syncthreads();
#pragma unroll
        for (int it = 0; it < 2; ++it) {
            int idx = it * 256 + tid;
            int row = idx >> 2, seg = idx & 3;
            *(s16x8*)&Ak[row][seg * 8] = *(const s16x8*)(Xb + (size_t)(m0 + row) * ODIM + k0 + seg * 8);
            *(s16x8*)&Bk[row][seg * 8] = *(const s16x8*)(Wb + (size_t)(n0 + row) * ODIM + k0 + seg * 8);
        }
        __syncthreads();

        s16x8 af[4], bfr[4];
#pragma unroll
        for (int i = 0; i < 4; ++i) af[i] = *(const s16x8*)&Ak[wr * 64 + i * 16 + l15][quad * 8];
#pragma unroll
        for (int j = 0; j < 4; ++j) bfr[j] = *(const s16x8*)&Bk[wc * 64 + j * 16 + l15][quad * 8];
#pragma unroll
        for (int i = 0; i < 4; ++i)
#pragma unroll
            for (int j = 0; j < 4; ++j)
                acc[i][j] = __builtin_amdgcn_mfma_f32_16x16x32_bf16(af[i], bfr[j], acc[i][j], 0, 0, 0);
    }

#pragma unroll
    for (int j = 0; j < 4; ++j) {
        int n = n0 + wc * 64 + j * 16 + l15;
        if (n >= DIM) continue;                 // N=384: only n0=256's upper half trims
        float bp = bproj[n];
#pragma unroll
        for (int i = 0; i < 4; ++i) {
            int mbase = m0 + wr * 64 + i * 16 + quad * 4;
#pragma unroll
            for (int r = 0; r < 4; ++r)
                out[(size_t)(mbase + r) * DIM + n] = acc[i][j][r] + bp;
        }
    }
}

// ---------------------------------------------------------------------------
// launch
// ---------------------------------------------------------------------------
extern "C" void kernel_launch(void* const* d_in, const int* in_sizes, int n_in,
                              void* d_out, int out_size, void* d_ws, size_t ws_size,
                              hipStream_t stream) {
    const float* x      = (const float*)d_in[0];  // (16,784,384)
    const float* Wqkv   = (const float*)d_in[1];  // (1536,384)
    const float* Wproj  = (const float*)d_in[2];  // (384,1024)
    const float* bproj  = (const float*)d_in[3];  // (384,)
    const float* table  = (const float*)d_in[4];  // (8,625)
    float* out = (float*)d_out;

    const size_t QK_SZ = (size_t)B_SZ * NH * L_SEQ * QKD;   // shorts
    const size_t V_SZ  = (size_t)B_SZ * NH * L_SEQ * VD;    // shorts
    const size_t BI_SZ = (size_t)NH * L_SEQ * L_SEQ;        // floats
    const size_t O2_SZ = (size_t)B_SZ * L_SEQ * ODIM;       // shorts
    const size_t X_SZ  = (size_t)B_SZ * L_SEQ * DIM;        // shorts
    const size_t WQ_SZ = (size_t)EDIM * DIM;                // shorts
    const size_t WP_SZ = (size_t)DIM * ODIM;                // shorts

    short* qb    = (short*)d_ws;
    short* kb    = qb + QK_SZ;
    short* vt    = kb + QK_SZ;
    float* bias  = (float*)(vt + V_SZ);
    short* o2    = (short*)(bias + BI_SZ);
    short* xb    = o2 + O2_SZ;
    short* wqkvb = xb + X_SZ;
    short* wprojb= wqkvb + WQ_SZ;
    float* wtab  = (float*)(wprojb + WP_SZ);
    int*   iyb   = (int*)(wtab + L_SEQ * 4);
    int*   ixb   = iyb + L_SEQ * 4;

    interp_tab_kernel<<<(L_SEQ + 255) / 256, 256, 0, stream>>>(wtab, iyb, ixb);

    {
        int total = NH * L_SEQ * L_SEQ;
        bias_kernel<<<(total + 255) / 256, 256, 0, stream>>>(table, wtab, iyb, ixb, bias);
    }

    // bulk fp32->bf16 conversions (hoisted out of GEMM staging)
    {
        int n8 = (int)(X_SZ / 8);
        cvt_bf16_kernel<<<(n8 + 255) / 256, 256, 0, stream>>>(x, xb, n8);
        n8 = (int)(WQ_SZ / 8);
        cvt_bf16_kernel<<<(n8 + 255) / 256, 256, 0, stream>>>(Wqkv, wqkvb, n8);
        n8 = (int)(WP_SZ / 8);
        cvt_bf16_kernel<<<(n8 + 255) / 256, 256, 0, stream>>>(Wproj, wprojb, n8);
    }

    {
        dim3 grid(12544 / 128, EDIM / 128);  // (98, 12)
        qkv_gemm_mfma<<<grid, 256, 0, stream>>>(xb, wqkvb, qb, kb, vt);
    }

    flash_attn_mfma3<<<B_SZ * NH * NQT, 256, 0, stream>>>(qb, kb, vt, bias, o2);

    {
        dim3 grid(12544 / 128, 3);           // N=384 -> 3 n-tiles of 128
        proj_gemm_mfma<<<grid, 256, 0, stream>>>(o2, wprojb, bproj, out);
    }
}